// Round 1
// 1131.687 us; speedup vs baseline: 1.0392x; 1.0392x over previous
//
#include <hip/hip_runtime.h>
#include <math.h>

#define NN 50000
#define FINN 64
#define HD 128
#define EE 800000
#define TT 8
#define PP 250000
#define DD 500000
#define GG 20000
#define VV 2000
#define OO 2

typedef short short8 __attribute__((ext_vector_type(8)));
typedef float f32x4 __attribute__((ext_vector_type(4)));

__device__ __forceinline__ unsigned short f2bf(float f) {
    unsigned int u = __float_as_uint(f);
    u += 0x7fffu + ((u >> 16) & 1u);   // round-to-nearest-even
    return (unsigned short)(u >> 16);
}
__device__ __forceinline__ float bf2f(unsigned short u) {
    return __uint_as_float(((unsigned int)u) << 16);
}

struct us8 { unsigned short v[8]; };

__device__ __forceinline__ void gload_lds16(const void* g, void* l) {
    __builtin_amdgcn_global_load_lds((__attribute__((address_space(1))) void*)g,
                                     (__attribute__((address_space(3))) void*)l, 16, 0, 0);
}

// ------------------------------------------------------------------
__global__ void count_k(const int* __restrict__ idx, int* __restrict__ counts, int n) {
    int i = blockIdx.x * blockDim.x + threadIdx.x;
    if (i < n) atomicAdd(&counts[idx[i]], 1);
}

// ---- 3-phase parallel exclusive scan for edge CSR rowptr ----
__global__ void blk_sum_k(const int* __restrict__ counts, int n, int* __restrict__ bsum) {
    __shared__ int buf[256];
    int t = threadIdx.x, i = blockIdx.x * 256 + t;
    buf[t] = (i < n) ? counts[i] : 0;
    __syncthreads();
    for (int off = 128; off > 0; off >>= 1) {
        if (t < off) buf[t] += buf[t + off];
        __syncthreads();
    }
    if (t == 0) bsum[blockIdx.x] = buf[0];
}

__global__ void scan_small_k(const int* __restrict__ bsum, int nb, int* __restrict__ boff) {
    __shared__ int buf[256];
    int t = threadIdx.x;
    int v = (t < nb) ? bsum[t] : 0;
    buf[t] = v;
    __syncthreads();
    for (int off = 1; off < 256; off <<= 1) {
        int u = (t >= off) ? buf[t - off] : 0;
        __syncthreads();
        buf[t] += u;
        __syncthreads();
    }
    if (t < nb) boff[t] = buf[t] - v;
}

__global__ void rowptr_fill_k(const int* __restrict__ counts, const int* __restrict__ boff,
                              int n, int* __restrict__ rowptr, int total) {
    __shared__ int buf[256];
    int t = threadIdx.x, i = blockIdx.x * 256 + t;
    int v = (i < n) ? counts[i] : 0;
    buf[t] = v;
    __syncthreads();
    for (int off = 1; off < 256; off <<= 1) {
        int u = (t >= off) ? buf[t - off] : 0;
        __syncthreads();
        buf[t] += u;
        __syncthreads();
    }
    if (i < n) rowptr[i] = boff[blockIdx.x] + buf[t] - v;
    if (i == 0) rowptr[n] = total;
}

// rowptr for SORTED arrays: rowptr[i] = lower_bound(arr, i), i in [0, m]
__global__ void lb_rowptr_k(const int* __restrict__ arr, int n, int* __restrict__ rowptr, int m) {
    int i = blockIdx.x * blockDim.x + threadIdx.x;
    if (i > m) return;
    int lo = 0, hi = n;
    while (lo < hi) {
        int mid = (lo + hi) >> 1;
        if (arr[mid] < i) lo = mid + 1; else hi = mid;
    }
    rowptr[i] = lo;
}

__global__ void fill_csr_k(const int* __restrict__ esrc, const int* __restrict__ edst,
                           const int* __restrict__ rowptr, int* __restrict__ cursor,
                           int* __restrict__ outi, int n) {
    int e = blockIdx.x * blockDim.x + threadIdx.x;
    if (e < n) {
        int d = edst[e];
        int pos = atomicAdd(&cursor[d], 1);
        outi[rowptr[d] + pos] = esrc[e];
    }
}

// ------------------------------------------------------------------
// t-bucket permutation
__global__ void hist9_k(const int* __restrict__ t_idx, int* __restrict__ hist) {
    __shared__ int l[9];
    if (threadIdx.x < 9) l[threadIdx.x] = 0;
    __syncthreads();
    int p = blockIdx.x * 256 + threadIdx.x;
    if (p < PP) atomicAdd(&l[t_idx[p]], 1);
    __syncthreads();
    if (threadIdx.x < 9) atomicAdd(&hist[threadIdx.x], l[threadIdx.x]);
}

__global__ void scan9_k(const int* __restrict__ hist, int* __restrict__ boff9) {
    if (threadIdx.x == 0) {
        int a = 0;
        for (int i = 0; i < 9; ++i) { boff9[i] = a; a += hist[i]; }
    }
}

__global__ void bucket_perm_k(const int* __restrict__ t_idx, const int* __restrict__ boff9,
                              int* __restrict__ cursor9, int* __restrict__ pperm) {
    __shared__ int lcnt[9];
    __shared__ int lbase[9];
    int tid = threadIdx.x;
    int p = blockIdx.x * 256 + tid;
    if (tid < 9) lcnt[tid] = 0;
    __syncthreads();
    int t = 0, lr = 0;
    bool ok = p < PP;
    if (ok) {
        t = t_idx[p];
        lr = atomicAdd(&lcnt[t], 1);
    }
    __syncthreads();
    if (tid < 9) lbase[tid] = atomicAdd(&cursor9[tid], lcnt[tid]);
    __syncthreads();
    if (ok) pperm[boff9[t] + lbase[t] + lr] = p;
}

// ------------------------------------------------------------------
// fused prep: x->bf16, both mp weight transposes, Wd1 transpose
__global__ void prep_k(const float* __restrict__ x,
                       const float* __restrict__ Wes, const float* __restrict__ Wen,
                       const float* __restrict__ W2s, const float* __restrict__ W2n,
                       const float* __restrict__ Wd1,
                       unsigned short* __restrict__ xb, unsigned short* __restrict__ wenc_t,
                       unsigned short* __restrict__ w2_t, unsigned short* __restrict__ wd1t) {
    int i = blockIdx.x * 256 + threadIdx.x;
    if (i < NN * FINN) xb[i] = f2bf(x[i]);
    if (i < HD * 2 * FINN) {
        int c = i / (2 * FINN), k = i - c * (2 * FINN);
        wenc_t[i] = f2bf((k < FINN) ? Wes[k * HD + c] : Wen[(k - FINN) * HD + c]);
    }
    if (i < HD * 2 * HD) {
        int c = i / (2 * HD), k = i - c * (2 * HD);
        w2_t[i] = f2bf((k < HD) ? W2s[k * HD + c] : W2n[(k - HD) * HD + c]);
    }
    if (i < 384 * 384) {
        int n = i / 384, k = i - n * 384;
        wd1t[i] = f2bf(Wd1[k * 384 + n]);
    }
}

// ------------------------------------------------------------------
// mean-aggregation, bf16 (R8-proven): 1 wave per node; 64/LPR sub-chains,
// depth-2 pipelined (2 row loads in flight per chain).
template <int KIN>
__launch_bounds__(256)
__global__ void agg2_k(const unsigned short* __restrict__ h, const int* __restrict__ rowptr,
                       const int* __restrict__ csr_src, unsigned short* __restrict__ aggout) {
    constexpr int LPR = KIN >> 3;      // lanes per row (ushort8 each)
    constexpr int EPW = 64 / LPR;      // chains per wave
    int node = blockIdx.x * 4 + (threadIdx.x >> 6);
    int lane = threadIdx.x & 63;
    int sub = lane / LPR;
    int fl = lane % LPR;
    if (node >= NN) return;
    int s = rowptr[node], e = rowptr[node + 1];
    float acc[8] = {};
    int i = s + sub;
    int iB = i + EPW;
    int srcA = (i < e) ? csr_src[i] : 0;
    int srcB = (iB < e) ? csr_src[iB] : 0;
    while (i < e) {
        bool hB = iB < e;
        us8 vA = *(const us8*)&h[(size_t)srcA * KIN + fl * 8];
        us8 vB;
        if (hB) vB = *(const us8*)&h[(size_t)srcB * KIN + fl * 8];
        int iN = iB + EPW, iN2 = iN + EPW;
        srcA = (iN < e) ? csr_src[iN] : 0;
        srcB = (iN2 < e) ? csr_src[iN2] : 0;
#pragma unroll
        for (int j = 0; j < 8; ++j) acc[j] += bf2f(vA.v[j]);
        if (hB) {
#pragma unroll
            for (int j = 0; j < 8; ++j) acc[j] += bf2f(vB.v[j]);
        }
        i = iN; iB = iN2;
    }
#pragma unroll
    for (int m = LPR; m < 64; m <<= 1)
#pragma unroll
        for (int j = 0; j < 8; ++j) acc[j] += __shfl_xor(acc[j], m);
    if (sub == 0) {
        float d = fmaxf((float)(e - s), 1.f);
        us8 o;
#pragma unroll
        for (int j = 0; j < 8; ++j) o.v[j] = f2bf(acc[j] / d);
        *(us8*)&aggout[(size_t)node * KIN + fl * 8] = o;
    }
}

// ------------------------------------------------------------------
// h_out = relu([hin | agg] @ Wt^T + b), bf16 MFMA, no LDS.
__launch_bounds__(128)
__global__ void mp_mfma_k(const unsigned short* __restrict__ hin,
                          const unsigned short* __restrict__ aggin,
                          const unsigned short* __restrict__ Wt,
                          const float* __restrict__ bias,
                          unsigned short* __restrict__ hout, int Kin) {
    int tid = threadIdx.x;
    int lane = tid & 63, w = tid >> 6;
    int cc = lane & 15, g = lane >> 4;
    int K = 2 * Kin;
    int rowA = blockIdx.x * 32 + w * 16 + cc;
    bool rowok = rowA < NN;
    const unsigned short* hrow = hin + (size_t)rowA * Kin;
    const unsigned short* arow = aggin + (size_t)rowA * Kin;

    f32x4 acc[8];
#pragma unroll
    for (int t = 0; t < 8; ++t) acc[t] = (f32x4){0.f, 0.f, 0.f, 0.f};

    for (int k0 = 0; k0 < K; k0 += 32) {
        int k = k0 + g * 8;
        short8 a = {0, 0, 0, 0, 0, 0, 0, 0};
        if (rowok)
            a = *(const short8*)((k < Kin) ? (hrow + k) : (arow + (k - Kin)));
#pragma unroll
        for (int t = 0; t < 8; ++t) {
            short8 b = *(const short8*)&Wt[(size_t)(t * 16 + cc) * K + k];
            acc[t] = __builtin_amdgcn_mfma_f32_16x16x32_bf16(a, b, acc[t], 0, 0, 0);
        }
    }
#pragma unroll
    for (int t = 0; t < 8; ++t) {
        int col = t * 16 + cc;
        float b1 = bias[col];
#pragma unroll
        for (int r = 0; r < 4; ++r) {
            int grow = blockIdx.x * 32 + w * 16 + g * 4 + r;
            if (grow < NN)
                hout[(size_t)grow * HD + col] = f2bf(fmaxf(acc[t][r] + b1, 0.f));
        }
    }
}

// ------------------------------------------------------------------
// dst segment-sum -> dstc[pi][128] bf16 in pperm-compact order.
__launch_bounds__(256)
__global__ void dst_sum_k(const unsigned short* __restrict__ feats,
                          const int* __restrict__ t_idx, const int* __restrict__ dst_nodes,
                          const int* __restrict__ dst_rowptr, const int* __restrict__ pperm,
                          unsigned short* __restrict__ dstc) {
    int pi = blockIdx.x * 4 + (threadIdx.x >> 6);
    int lane = threadIdx.x & 63;
    int sub = lane >> 4;
    int fl = lane & 15;
    if (pi >= PP) return;
    int p = pperm[pi];
    long t = t_idx[p];
    const unsigned short* base = feats + t * (long)NN * HD;
    int s = dst_rowptr[p], e = dst_rowptr[p + 1];
    float acc[8] = {};
    int i = s + sub;
    int nd_next = (i < e) ? dst_nodes[i] : 0;
    for (; i < e; i += 4) {
        int nd = nd_next;
        int in = i + 4;
        if (in < e) nd_next = dst_nodes[in];
        us8 v = *(const us8*)&base[(size_t)nd * HD + fl * 8];
#pragma unroll
        for (int j = 0; j < 8; ++j) acc[j] += bf2f(v.v[j]);
    }
#pragma unroll
    for (int m = 16; m < 64; m <<= 1)
#pragma unroll
        for (int j = 0; j < 8; ++j) acc[j] += __shfl_xor(acc[j], m);
    if (sub == 0) {
        us8 o;
#pragma unroll
        for (int j = 0; j < 8; ++j) o.v[j] = f2bf(acc[j]);
        *(us8*)&dstc[(size_t)pi * HD + fl * 8] = o;
    }
}

// ------------------------------------------------------------------
// dec3: LDS-staged decoder. Per block of 64 predictions, stage the full
// A-panel (64 rows x 3 sections x 256 B = 48 KB) into LDS via
// global_load_lds_dwordx4 (12 back-to-back gathers per wave -> deep MLP),
// then a pure LDS->MFMA loop. Source-chunk XOR swizzle (chunk ^= row&7)
// gives conflict-free ds_read_b128 with a linear gload_lds destination.
__launch_bounds__(256)
__global__ void dec3_k(const unsigned short* __restrict__ feats,
                       const unsigned short* __restrict__ dstc,
                       const int* __restrict__ place_idx, const int* __restrict__ src_idx,
                       const int* __restrict__ t_idx, const int* __restrict__ group_id,
                       const int* __restrict__ pperm,
                       const unsigned short* __restrict__ Wd1t,
                       const float* __restrict__ bd1, const float* __restrict__ Wd2,
                       const float* __restrict__ bd2, float* __restrict__ logprob,
                       float* __restrict__ group_sums) {
    __shared__ unsigned short lds_a[192 * 128];           // 48 KB staged A panel
    __shared__ const unsigned short* rowbase[192];        // per-row global base
    __shared__ float lpart[4][64][2];

    int tid = threadIdx.x;
    int lane = tid & 63, w = tid >> 6;
    int cc = lane & 15, gq = lane >> 4;
    int p0 = blockIdx.x * 64;

    // phase 0: compute the 192 row base pointers (sec: 0=place, 1=src, 2=dst)
    if (tid < 192) {
        int sec = tid >> 6, pl = tid & 63;
        int pic = min(p0 + pl, PP - 1);
        const unsigned short* b;
        if (sec == 2) {
            b = dstc + (size_t)pic * HD;
        } else {
            int p = pperm[pic];
            long t = t_idx[p];
            int node = (sec == 0) ? place_idx[p] : src_idx[p];
            b = feats + ((t * NN + node) * (long)HD);
        }
        rowbase[tid] = b;
    }
    __syncthreads();

    // phase 1: stage 48 rows per wave (12 x global_load_lds dwordx4).
    // lane l covers row (l>>4), chunk (l&15); source chunk pre-swizzled.
    {
        int chunk = lane & 15;
        int rsub = lane >> 4;
#pragma unroll
        for (int i = 0; i < 12; ++i) {
            int r = w * 48 + i * 4 + rsub;
            const unsigned short* src = rowbase[r] + ((chunk ^ (r & 7)) * 8);
            gload_lds16(src, &lds_a[(size_t)(w * 48 + i * 4) * 128]);
        }
    }
    __syncthreads();   // compiler drains vmcnt before s_barrier

    // phase 2: MFMA from LDS
    f32x4 acc[4][6];
#pragma unroll
    for (int s = 0; s < 4; ++s)
#pragma unroll
        for (int t = 0; t < 6; ++t) acc[s][t] = (f32x4){0.f, 0.f, 0.f, 0.f};

    const unsigned short* bbase = Wd1t + ((long)(w * 96 + cc) * 384 + gq * 8);
    int cx7 = cc & 7;

#pragma unroll
    for (int kk = 0; kk < 12; ++kk) {
        int sec = kk >> 2;
        int cbase = (kk & 3) * 4 + gq;          // global 16B-chunk index in row
        int coff = (cbase ^ cx7) * 8;           // swizzled LDS offset (ushorts)
        short8 a_c[4];
#pragma unroll
        for (int s = 0; s < 4; ++s) {
            int lrow = sec * 64 + s * 16 + cc;
            a_c[s] = *(const short8*)&lds_a[(size_t)lrow * 128 + coff];
        }
#pragma unroll
        for (int t = 0; t < 6; ++t) {
            short8 b = *(const short8*)(bbase + (long)t * 16 * 384 + kk * 32);
#pragma unroll
            for (int s = 0; s < 4; ++s)
                acc[s][t] = __builtin_amdgcn_mfma_f32_16x16x32_bf16(a_c[s], b, acc[s][t], 0, 0, 0);
        }
    }

    // epilogue: bias + relu + Wd2 partials, reduce over the 16 cc lanes
    float part[4][4][2] = {};
#pragma unroll
    for (int t = 0; t < 6; ++t) {
        int col = w * 96 + t * 16 + cc;
        float b1 = bd1[col];
        float w0 = Wd2[col * 2 + 0], w1 = Wd2[col * 2 + 1];
#pragma unroll
        for (int s = 0; s < 4; ++s)
#pragma unroll
            for (int r = 0; r < 4; ++r) {
                float h = fmaxf(acc[s][t][r] + b1, 0.f);
                part[s][r][0] += h * w0;
                part[s][r][1] += h * w1;
            }
    }
#pragma unroll
    for (int m = 1; m < 16; m <<= 1)
#pragma unroll
        for (int s = 0; s < 4; ++s)
#pragma unroll
            for (int r = 0; r < 4; ++r) {
                part[s][r][0] += __shfl_xor(part[s][r][0], m);
                part[s][r][1] += __shfl_xor(part[s][r][1], m);
            }
    if (cc == 0) {
#pragma unroll
        for (int s = 0; s < 4; ++s)
#pragma unroll
            for (int r = 0; r < 4; ++r) {
                int row = s * 16 + gq * 4 + r;
                lpart[w][row][0] = part[s][r][0];
                lpart[w][row][1] = part[s][r][1];
            }
    }
    __syncthreads();
    if (tid < 64) {
        int pi = p0 + tid;
        if (pi < PP) {
            int p = pperm[pi];
            float l0 = lpart[0][tid][0] + lpart[1][tid][0] + lpart[2][tid][0] + lpart[3][tid][0] + bd2[0];
            float l1 = lpart[0][tid][1] + lpart[1][tid][1] + lpart[2][tid][1] + lpart[3][tid][1] + bd2[1];
            float m = fmaxf(l0, l1);
            float lse = m + logf(expf(l0 - m) + expf(l1 - m));
            float lp0 = l0 - lse, lp1 = l1 - lse;
            logprob[p * 2 + 0] = lp0;
            logprob[p * 2 + 1] = lp1;
            int g = group_id[p];
            atomicAdd(&group_sums[g * 2 + 0], lp0);
            atomicAdd(&group_sums[g * 2 + 1], lp1);
        }
    }
}

// ------------------------------------------------------------------
// single block: counts total + segmented inclusive cumsum within variants
__global__ void within_total_k(const float* __restrict__ group_sums,
                               const int* __restrict__ var_rowptr,
                               const float* __restrict__ counts,
                               float* __restrict__ within, float* __restrict__ total) {
    __shared__ float buf[256];
    int tid = threadIdx.x;
    float s = 0.f;
    for (int i = tid; i < VV; i += 256) s += counts[i];
    buf[tid] = s;
    __syncthreads();
    for (int off = 128; off > 0; off >>= 1) {
        if (tid < off) buf[tid] += buf[tid + off];
        __syncthreads();
    }
    if (tid == 0) total[0] = buf[0];
    for (int v = tid; v < VV; v += 256) {
        int gs = var_rowptr[v], ge = var_rowptr[v + 1];
        float r0 = 0.f, r1 = 0.f;
        for (int g = gs; g < ge; ++g) {
            r0 += group_sums[2 * g + 0];
            r1 += group_sums[2 * g + 1];
            within[2 * g + 0] = r0;
            within[2 * g + 1] = r1;
        }
    }
}

__global__ void final_k(const float* __restrict__ logprob, const float* __restrict__ within,
                        const int* __restrict__ group_id, const int* __restrict__ vog,
                        const float* __restrict__ counts, const float* __restrict__ total,
                        const int* __restrict__ place_idx, float* __restrict__ outp) {
    int p = blockIdx.x * blockDim.x + threadIdx.x;
    if (p >= PP) return;
    int g = group_id[p];
    int v = vog[g];
    float lc = logf(counts[v]) - logf(total[0]);
    int node = place_idx[p];
    atomicAdd(&outp[node * 2 + 0], logprob[p * 2 + 0] + within[g * 2 + 0] + lc);
    atomicAdd(&outp[node * 2 + 1], logprob[p * 2 + 1] + within[g * 2 + 1] + lc);
}

// ------------------------------------------------------------------
extern "C" void kernel_launch(void* const* d_in, const int* in_sizes, int n_in,
                              void* d_out, int out_size, void* d_ws, size_t ws_size,
                              hipStream_t stream) {
    const float* x          = (const float*)d_in[0];
    const float* W_enc_self = (const float*)d_in[1];
    const float* W_enc_nei  = (const float*)d_in[2];
    const float* b_enc      = (const float*)d_in[3];
    const float* W2_self    = (const float*)d_in[4];
    const float* W2_nei     = (const float*)d_in[5];
    const float* b2         = (const float*)d_in[6];
    const float* Wd1        = (const float*)d_in[7];
    const float* bd1        = (const float*)d_in[8];
    const float* Wd2        = (const float*)d_in[9];
    const float* bd2        = (const float*)d_in[10];
    const float* counts     = (const float*)d_in[11];
    const int* edge_src     = (const int*)d_in[12];
    const int* edge_dst     = (const int*)d_in[13];
    const int* place_idx    = (const int*)d_in[14];
    const int* src_idx      = (const int*)d_in[15];
    const int* t_idx        = (const int*)d_in[16];
    const int* dst_nodes    = (const int*)d_in[17];
    const int* dst_seg      = (const int*)d_in[18];
    const int* group_id     = (const int*)d_in[19];
    const int* variant_of_group = (const int*)d_in[20];
    float* outp = (float*)d_out;

    const int NB = (NN + 255) / 256;   // 196 scan blocks

    // ---- workspace layout (R10-identical) ----
    unsigned short* feats = (unsigned short*)d_ws;              // 9*N*H bf16
    unsigned short* aggb  = feats + (size_t)(TT + 1) * NN * HD; // N*H
    unsigned short* xb    = aggb + (size_t)NN * HD;             // N*FIN
    unsigned short* dstc  = xb + (size_t)NN * FINN;             // P*H bf16 (pperm-compact)
    unsigned short* wenc_t = dstc + (size_t)PP * HD;            // 128*128
    unsigned short* w2_t   = wenc_t + HD * 2 * FINN;            // 128*256
    unsigned short* wd1t   = w2_t + HD * 2 * HD;                // 384*384
    int* zr = (int*)(wd1t + 384 * 384);                         // zero-region start
    int* csr_counts   = zr;                                     // N
    int* csr_cursor   = csr_counts + NN;                        // N
    float* group_sums = (float*)(csr_cursor + NN);              // 2G
    int* hist9        = (int*)(group_sums + 2 * GG);            // 9
    int* cursor9      = hist9 + 9;                              // 9
    size_t zero_words = (size_t)NN + NN + 2 * GG + 18;
    int* bsum       = cursor9 + 9;                              // 256
    int* boff       = bsum + 256;                               // 256
    int* boff9      = boff + 256;                               // 9 (+pad 7)
    int* csr_rowptr = boff9 + 16;                               // N+1
    int* dst_rowptr = csr_rowptr + (NN + 1);                    // P+1
    int* var_rowptr = dst_rowptr + (PP + 1);                    // V+1
    int* csr_src    = var_rowptr + (VV + 1);                    // E
    int* pperm      = csr_src + EE;                             // P
    float* logprob  = (float*)(pperm + PP);                     // 2P
    float* within   = logprob + 2 * PP;                         // 2G
    float* total_counts = within + 2 * GG;                      // 1

    hipMemsetAsync(zr, 0, zero_words * 4, stream);
    hipMemsetAsync(d_out, 0, (size_t)out_size * sizeof(float), stream);

    // ---- fused prep + CSR builds + t-bucket permutation ----
    prep_k<<<(NN * FINN + 255) / 256, 256, 0, stream>>>(x, W_enc_self, W_enc_nei, W2_self,
                                                        W2_nei, Wd1, xb, wenc_t, w2_t, wd1t);
    count_k<<<(EE + 255) / 256, 256, 0, stream>>>(edge_dst, csr_counts, EE);
    blk_sum_k<<<NB, 256, 0, stream>>>(csr_counts, NN, bsum);
    scan_small_k<<<1, 256, 0, stream>>>(bsum, NB, boff);
    rowptr_fill_k<<<NB, 256, 0, stream>>>(csr_counts, boff, NN, csr_rowptr, EE);
    fill_csr_k<<<(EE + 255) / 256, 256, 0, stream>>>(edge_src, edge_dst, csr_rowptr,
                                                     csr_cursor, csr_src, EE);
    lb_rowptr_k<<<(PP + 256) / 256, 256, 0, stream>>>(dst_seg, DD, dst_rowptr, PP);
    lb_rowptr_k<<<(VV + 256) / 256, 256, 0, stream>>>(variant_of_group, GG, var_rowptr, VV);
    hist9_k<<<(PP + 255) / 256, 256, 0, stream>>>(t_idx, hist9);
    scan9_k<<<1, 64, 0, stream>>>(hist9, boff9);
    bucket_perm_k<<<(PP + 255) / 256, 256, 0, stream>>>(t_idx, boff9, cursor9, pperm);

    // ---- 9 message-passing rounds (R8-proven agg2 + wider-grid mp) ----
    for (int r = 0; r <= TT; ++r) {
        const unsigned short* hin = (r == 0) ? xb : feats + (size_t)(r - 1) * NN * HD;
        unsigned short* hout = feats + (size_t)r * NN * HD;
        if (r == 0) {
            agg2_k<FINN><<<(NN + 3) / 4, 256, 0, stream>>>(hin, csr_rowptr, csr_src, aggb);
            mp_mfma_k<<<(NN + 31) / 32, 128, 0, stream>>>(hin, aggb, wenc_t, b_enc, hout, FINN);
        } else {
            agg2_k<HD><<<(NN + 3) / 4, 256, 0, stream>>>(hin, csr_rowptr, csr_src, aggb);
            mp_mfma_k<<<(NN + 31) / 32, 128, 0, stream>>>(hin, aggb, w2_t, b2, hout, HD);
        }
    }

    // ---- dst segment-sum (pperm-compact) + LDS-staged dec3 decoder ----
    dst_sum_k<<<(PP + 3) / 4, 256, 0, stream>>>(feats, t_idx, dst_nodes, dst_rowptr, pperm, dstc);
    dec3_k<<<(PP + 63) / 64, 256, 0, stream>>>(feats, dstc, place_idx, src_idx, t_idx,
                                               group_id, pperm, wd1t, bd1, Wd2, bd2,
                                               logprob, group_sums);

    // ---- tail ----
    within_total_k<<<1, 256, 0, stream>>>(group_sums, var_rowptr, counts, within, total_counts);
    final_k<<<(PP + 255) / 256, 256, 0, stream>>>(logprob, within, group_id, variant_of_group,
                                                  counts, total_counts, place_idx, outp);
}

// Round 2
// 1084.355 us; speedup vs baseline: 1.0846x; 1.0436x over previous
//
#include <hip/hip_runtime.h>
#include <math.h>

#define NN 50000
#define FINN 64
#define HD 128
#define EE 800000
#define TT 8
#define PP 250000
#define DD 500000
#define GG 20000
#define VV 2000
#define OO 2

#define DEC_GRID 256
#define DEC_TILES ((PP + 63) / 64)

typedef short short8 __attribute__((ext_vector_type(8)));
typedef float f32x4 __attribute__((ext_vector_type(4)));

__device__ __forceinline__ unsigned short f2bf(float f) {
    unsigned int u = __float_as_uint(f);
    u += 0x7fffu + ((u >> 16) & 1u);   // round-to-nearest-even
    return (unsigned short)(u >> 16);
}
__device__ __forceinline__ float bf2f(unsigned short u) {
    return __uint_as_float(((unsigned int)u) << 16);
}

struct us8 { unsigned short v[8]; };

__device__ __forceinline__ void gload_lds16(const void* g, void* l) {
    __builtin_amdgcn_global_load_lds((__attribute__((address_space(1))) void*)g,
                                     (__attribute__((address_space(3))) void*)l, 16, 0, 0);
}

// ------------------------------------------------------------------
__global__ void count_k(const int* __restrict__ idx, int* __restrict__ counts, int n) {
    int i = blockIdx.x * blockDim.x + threadIdx.x;
    if (i < n) atomicAdd(&counts[idx[i]], 1);
}

// ---- 3-phase parallel exclusive scan for edge CSR rowptr ----
__global__ void blk_sum_k(const int* __restrict__ counts, int n, int* __restrict__ bsum) {
    __shared__ int buf[256];
    int t = threadIdx.x, i = blockIdx.x * 256 + t;
    buf[t] = (i < n) ? counts[i] : 0;
    __syncthreads();
    for (int off = 128; off > 0; off >>= 1) {
        if (t < off) buf[t] += buf[t + off];
        __syncthreads();
    }
    if (t == 0) bsum[blockIdx.x] = buf[0];
}

__global__ void scan_small_k(const int* __restrict__ bsum, int nb, int* __restrict__ boff) {
    __shared__ int buf[256];
    int t = threadIdx.x;
    int v = (t < nb) ? bsum[t] : 0;
    buf[t] = v;
    __syncthreads();
    for (int off = 1; off < 256; off <<= 1) {
        int u = (t >= off) ? buf[t - off] : 0;
        __syncthreads();
        buf[t] += u;
        __syncthreads();
    }
    if (t < nb) boff[t] = buf[t] - v;
}

__global__ void rowptr_fill_k(const int* __restrict__ counts, const int* __restrict__ boff,
                              int n, int* __restrict__ rowptr, int total) {
    __shared__ int buf[256];
    int t = threadIdx.x, i = blockIdx.x * 256 + t;
    int v = (i < n) ? counts[i] : 0;
    buf[t] = v;
    __syncthreads();
    for (int off = 1; off < 256; off <<= 1) {
        int u = (t >= off) ? buf[t - off] : 0;
        __syncthreads();
        buf[t] += u;
        __syncthreads();
    }
    if (i < n) rowptr[i] = boff[blockIdx.x] + buf[t] - v;
    if (i == 0) rowptr[n] = total;
}

// rowptr for SORTED arrays: rowptr[i] = lower_bound(arr, i), i in [0, m]
__global__ void lb_rowptr_k(const int* __restrict__ arr, int n, int* __restrict__ rowptr, int m) {
    int i = blockIdx.x * blockDim.x + threadIdx.x;
    if (i > m) return;
    int lo = 0, hi = n;
    while (lo < hi) {
        int mid = (lo + hi) >> 1;
        if (arr[mid] < i) lo = mid + 1; else hi = mid;
    }
    rowptr[i] = lo;
}

__global__ void fill_csr_k(const int* __restrict__ esrc, const int* __restrict__ edst,
                           const int* __restrict__ rowptr, int* __restrict__ cursor,
                           int* __restrict__ outi, int n) {
    int e = blockIdx.x * blockDim.x + threadIdx.x;
    if (e < n) {
        int d = edst[e];
        int pos = atomicAdd(&cursor[d], 1);
        outi[rowptr[d] + pos] = esrc[e];
    }
}

// ------------------------------------------------------------------
// t-bucket permutation
__global__ void hist9_k(const int* __restrict__ t_idx, int* __restrict__ hist) {
    __shared__ int l[9];
    if (threadIdx.x < 9) l[threadIdx.x] = 0;
    __syncthreads();
    int p = blockIdx.x * 256 + threadIdx.x;
    if (p < PP) atomicAdd(&l[t_idx[p]], 1);
    __syncthreads();
    if (threadIdx.x < 9) atomicAdd(&hist[threadIdx.x], l[threadIdx.x]);
}

__global__ void scan9_k(const int* __restrict__ hist, int* __restrict__ boff9) {
    if (threadIdx.x == 0) {
        int a = 0;
        for (int i = 0; i < 9; ++i) { boff9[i] = a; a += hist[i]; }
    }
}

__global__ void bucket_perm_k(const int* __restrict__ t_idx, const int* __restrict__ boff9,
                              int* __restrict__ cursor9, int* __restrict__ pperm) {
    __shared__ int lcnt[9];
    __shared__ int lbase[9];
    int tid = threadIdx.x;
    int p = blockIdx.x * 256 + tid;
    if (tid < 9) lcnt[tid] = 0;
    __syncthreads();
    int t = 0, lr = 0;
    bool ok = p < PP;
    if (ok) {
        t = t_idx[p];
        lr = atomicAdd(&lcnt[t], 1);
    }
    __syncthreads();
    if (tid < 9) lbase[tid] = atomicAdd(&cursor9[tid], lcnt[tid]);
    __syncthreads();
    if (ok) pperm[boff9[t] + lbase[t] + lr] = p;
}

// ------------------------------------------------------------------
// fused prep: x->bf16, both mp weight transposes, Wd1 transpose
__global__ void prep_k(const float* __restrict__ x,
                       const float* __restrict__ Wes, const float* __restrict__ Wen,
                       const float* __restrict__ W2s, const float* __restrict__ W2n,
                       const float* __restrict__ Wd1,
                       unsigned short* __restrict__ xb, unsigned short* __restrict__ wenc_t,
                       unsigned short* __restrict__ w2_t, unsigned short* __restrict__ wd1t) {
    int i = blockIdx.x * 256 + threadIdx.x;
    if (i < NN * FINN) xb[i] = f2bf(x[i]);
    if (i < HD * 2 * FINN) {
        int c = i / (2 * FINN), k = i - c * (2 * FINN);
        wenc_t[i] = f2bf((k < FINN) ? Wes[k * HD + c] : Wen[(k - FINN) * HD + c]);
    }
    if (i < HD * 2 * HD) {
        int c = i / (2 * HD), k = i - c * (2 * HD);
        w2_t[i] = f2bf((k < HD) ? W2s[k * HD + c] : W2n[(k - HD) * HD + c]);
    }
    if (i < 384 * 384) {
        int n = i / 384, k = i - n * 384;
        wd1t[i] = f2bf(Wd1[k * 384 + n]);
    }
}

// ------------------------------------------------------------------
// mean-aggregation, bf16 (R8-proven): 1 wave per node; 64/LPR sub-chains,
// depth-2 pipelined (2 row loads in flight per chain).
template <int KIN>
__launch_bounds__(256)
__global__ void agg2_k(const unsigned short* __restrict__ h, const int* __restrict__ rowptr,
                       const int* __restrict__ csr_src, unsigned short* __restrict__ aggout) {
    constexpr int LPR = KIN >> 3;      // lanes per row (ushort8 each)
    constexpr int EPW = 64 / LPR;      // chains per wave
    int node = blockIdx.x * 4 + (threadIdx.x >> 6);
    int lane = threadIdx.x & 63;
    int sub = lane / LPR;
    int fl = lane % LPR;
    if (node >= NN) return;
    int s = rowptr[node], e = rowptr[node + 1];
    float acc[8] = {};
    int i = s + sub;
    int iB = i + EPW;
    int srcA = (i < e) ? csr_src[i] : 0;
    int srcB = (iB < e) ? csr_src[iB] : 0;
    while (i < e) {
        bool hB = iB < e;
        us8 vA = *(const us8*)&h[(size_t)srcA * KIN + fl * 8];
        us8 vB;
        if (hB) vB = *(const us8*)&h[(size_t)srcB * KIN + fl * 8];
        int iN = iB + EPW, iN2 = iN + EPW;
        srcA = (iN < e) ? csr_src[iN] : 0;
        srcB = (iN2 < e) ? csr_src[iN2] : 0;
#pragma unroll
        for (int j = 0; j < 8; ++j) acc[j] += bf2f(vA.v[j]);
        if (hB) {
#pragma unroll
            for (int j = 0; j < 8; ++j) acc[j] += bf2f(vB.v[j]);
        }
        i = iN; iB = iN2;
    }
#pragma unroll
    for (int m = LPR; m < 64; m <<= 1)
#pragma unroll
        for (int j = 0; j < 8; ++j) acc[j] += __shfl_xor(acc[j], m);
    if (sub == 0) {
        float d = fmaxf((float)(e - s), 1.f);
        us8 o;
#pragma unroll
        for (int j = 0; j < 8; ++j) o.v[j] = f2bf(acc[j] / d);
        *(us8*)&aggout[(size_t)node * KIN + fl * 8] = o;
    }
}

// ------------------------------------------------------------------
// h_out = relu([hin | agg] @ Wt^T + b), bf16 MFMA, no LDS.
__launch_bounds__(128)
__global__ void mp_mfma_k(const unsigned short* __restrict__ hin,
                          const unsigned short* __restrict__ aggin,
                          const unsigned short* __restrict__ Wt,
                          const float* __restrict__ bias,
                          unsigned short* __restrict__ hout, int Kin) {
    int tid = threadIdx.x;
    int lane = tid & 63, w = tid >> 6;
    int cc = lane & 15, g = lane >> 4;
    int K = 2 * Kin;
    int rowA = blockIdx.x * 32 + w * 16 + cc;
    bool rowok = rowA < NN;
    const unsigned short* hrow = hin + (size_t)rowA * Kin;
    const unsigned short* arow = aggin + (size_t)rowA * Kin;

    f32x4 acc[8];
#pragma unroll
    for (int t = 0; t < 8; ++t) acc[t] = (f32x4){0.f, 0.f, 0.f, 0.f};

    for (int k0 = 0; k0 < K; k0 += 32) {
        int k = k0 + g * 8;
        short8 a = {0, 0, 0, 0, 0, 0, 0, 0};
        if (rowok)
            a = *(const short8*)((k < Kin) ? (hrow + k) : (arow + (k - Kin)));
#pragma unroll
        for (int t = 0; t < 8; ++t) {
            short8 b = *(const short8*)&Wt[(size_t)(t * 16 + cc) * K + k];
            acc[t] = __builtin_amdgcn_mfma_f32_16x16x32_bf16(a, b, acc[t], 0, 0, 0);
        }
    }
#pragma unroll
    for (int t = 0; t < 8; ++t) {
        int col = t * 16 + cc;
        float b1 = bias[col];
#pragma unroll
        for (int r = 0; r < 4; ++r) {
            int grow = blockIdx.x * 32 + w * 16 + g * 4 + r;
            if (grow < NN)
                hout[(size_t)grow * HD + col] = f2bf(fmaxf(acc[t][r] + b1, 0.f));
        }
    }
}

// ------------------------------------------------------------------
// dst segment-sum -> dstc[pi][128] bf16 in pperm-compact order.
__launch_bounds__(256)
__global__ void dst_sum_k(const unsigned short* __restrict__ feats,
                          const int* __restrict__ t_idx, const int* __restrict__ dst_nodes,
                          const int* __restrict__ dst_rowptr, const int* __restrict__ pperm,
                          unsigned short* __restrict__ dstc) {
    int pi = blockIdx.x * 4 + (threadIdx.x >> 6);
    int lane = threadIdx.x & 63;
    int sub = lane >> 4;
    int fl = lane & 15;
    if (pi >= PP) return;
    int p = pperm[pi];
    long t = t_idx[p];
    const unsigned short* base = feats + t * (long)NN * HD;
    int s = dst_rowptr[p], e = dst_rowptr[p + 1];
    float acc[8] = {};
    int i = s + sub;
    int nd_next = (i < e) ? dst_nodes[i] : 0;
    for (; i < e; i += 4) {
        int nd = nd_next;
        int in = i + 4;
        if (in < e) nd_next = dst_nodes[in];
        us8 v = *(const us8*)&base[(size_t)nd * HD + fl * 8];
#pragma unroll
        for (int j = 0; j < 8; ++j) acc[j] += bf2f(v.v[j]);
    }
#pragma unroll
    for (int m = 16; m < 64; m <<= 1)
#pragma unroll
        for (int j = 0; j < 8; ++j) acc[j] += __shfl_xor(acc[j], m);
    if (sub == 0) {
        us8 o;
#pragma unroll
        for (int j = 0; j < 8; ++j) o.v[j] = f2bf(acc[j]);
        *(us8*)&dstc[(size_t)pi * HD + fl * 8] = o;
    }
}

// ------------------------------------------------------------------
// dec4: persistent pipelined decoder. 256 blocks (1/CU), each owns ~16
// tiles of 64 predictions. Double-buffered 2x48KB LDS A-panel staged via
// global_load_lds; counted s_waitcnt vmcnt(15) (never 0) keeps the next
// tile's 12 gathers + 3 index loads in flight across barriers. Wd1t
// B-operand held in 288 VGPRs for the whole block (1 wave/SIMD -> 512-reg
// budget), so the compute phase has ZERO VMEM and cannot disturb vmcnt.
// Index pointer-chase (pperm -> t_idx/place/src) pipelined 2 tiles ahead.
__launch_bounds__(256, 1)
__global__ void dec4_k(const unsigned short* __restrict__ feats,
                       const unsigned short* __restrict__ dstc,
                       const int* __restrict__ place_idx, const int* __restrict__ src_idx,
                       const int* __restrict__ t_idx, const int* __restrict__ group_id,
                       const int* __restrict__ pperm,
                       const unsigned short* __restrict__ Wd1t,
                       const float* __restrict__ bd1, const float* __restrict__ Wd2,
                       const float* __restrict__ bd2, float* __restrict__ logprob,
                       float* __restrict__ group_sums) {
    __shared__ unsigned short buf[2][192 * 128];          // 2 x 48 KB A-panel
    __shared__ unsigned long long rb[2][192];             // row-base double buffer
    __shared__ float lpart[4][64][2];

    int tid = threadIdx.x;
    int lane = tid & 63, w = tid >> 6;
    int cc = lane & 15, gq = lane >> 4;
    int cx7 = cc & 7;
    int bid = blockIdx.x;

    int row = min(tid, 191);
    int sec = row >> 6, pl = row & 63;
    const int* nptr = (sec == 0) ? place_idx : src_idx;

    int nt = (DEC_TILES - 1 - bid) / DEC_GRID + 1;        // tiles this block owns

    // ---- prologue: indices for tiles 0,1; pperm for tile 2 ----
    int pic0 = min(bid * 64 + pl, PP - 1);
    int pic1 = min((bid + DEC_GRID) * 64 + pl, PP - 1);
    int pic2p = min((bid + 2 * DEC_GRID) * 64 + pl, PP - 1);
    int pA = pperm[pic0], pB = pperm[pic1];
    int preg = pperm[pic2p];
    int tA = t_idx[pA], tB = t_idx[pB];
    int nA = nptr[pA], nB = nptr[pB];
    if (tid < 192) {
        rb[0][tid] = (sec == 2) ? (unsigned long long)(dstc + (size_t)pic0 * HD)
                                : (unsigned long long)(feats + (((long)tA * NN + nA) * (long)HD));
        rb[1][tid] = (sec == 2) ? (unsigned long long)(dstc + (size_t)pic1 * HD)
                                : (unsigned long long)(feats + (((long)tB * NN + nB) * (long)HD));
    }

    // ---- B-operand into registers (block-invariant) ----
    short8 breg[72];
    {
        const unsigned short* bbase = Wd1t + ((long)(w * 96 + cc) * 384 + gq * 8);
#pragma unroll
        for (int kk = 0; kk < 12; ++kk)
#pragma unroll
            for (int t = 0; t < 6; ++t)
                breg[kk * 6 + t] = *(const short8*)(bbase + (long)t * 16 * 384 + kk * 32);
    }
    __syncthreads();   // prologue full drain is fine (once)

    int rsub = lane >> 4, chunk = lane & 15;

    // stage tile parity 'par' (12 gload_lds per wave, src chunk-swizzled)
#define STAGE(par_)                                                                  \
    {                                                                                \
        _Pragma("unroll")                                                            \
        for (int i = 0; i < 12; ++i) {                                               \
            int r = w * 48 + i * 4 + rsub;                                           \
            const unsigned short* src =                                              \
                (const unsigned short*)rb[par_][r] + ((chunk ^ (r & 7)) * 8);        \
            gload_lds16(src, &buf[par_][(w * 48 + i * 4) * 128]);                    \
        }                                                                            \
    }

    STAGE(0);   // tile 0 in flight (12 outstanding)

    for (int k = 0; k < nt; ++k) {
        int par = k & 1, npar = par ^ 1;
        int tl = bid + k * DEC_GRID;

        // --- idx loads for tile k+2 (3 VMEM, uniform across all waves) ---
        int tload = t_idx[preg];
        int nload = nptr[preg];
        int pic3v = min((bid + (k + 3) * DEC_GRID) * 64 + pl, PP - 1);
        int preg2 = pperm[pic3v];
        int pic2v = min((bid + (k + 2) * DEC_GRID) * 64 + pl, PP - 1);

        // --- stage tile k+1 (12 VMEM) ---
        STAGE(npar);

        // --- counted wait: completes stage(k) (oldest 12), leaves the
        //     newest 15 (3 idx + 12 stage k+1) in flight ---
        __builtin_amdgcn_sched_barrier(0);
        asm volatile("s_waitcnt vmcnt(15)" ::: "memory");
        __builtin_amdgcn_s_barrier();
        __builtin_amdgcn_sched_barrier(0);

        // --- compute tile k from buf[par] (zero VMEM in this phase) ---
        const unsigned short* bufc = &buf[par][0];
        f32x4 acc[4][6];
#pragma unroll
        for (int s = 0; s < 4; ++s)
#pragma unroll
            for (int t = 0; t < 6; ++t) acc[s][t] = (f32x4){0.f, 0.f, 0.f, 0.f};

#pragma unroll
        for (int kk = 0; kk < 12; ++kk) {
            int seck = kk >> 2;
            int cbase = (kk & 3) * 4 + gq;
            int coff = (cbase ^ cx7) * 8;
            short8 a_c[4];
#pragma unroll
            for (int s = 0; s < 4; ++s) {
                int lrow = seck * 64 + s * 16 + cc;
                a_c[s] = *(const short8*)&bufc[lrow * 128 + coff];
            }
#pragma unroll
            for (int t = 0; t < 6; ++t)
#pragma unroll
                for (int s = 0; s < 4; ++s)
                    acc[s][t] = __builtin_amdgcn_mfma_f32_16x16x32_bf16(a_c[s], breg[kk * 6 + t],
                                                                        acc[s][t], 0, 0, 0);
        }

        // --- epilogue: bias + relu + Wd2 partials, cc-lane reduce ---
        float part[4][4][2] = {};
#pragma unroll
        for (int t = 0; t < 6; ++t) {
            int col = w * 96 + t * 16 + cc;
            float b1 = bd1[col];
            float w0 = Wd2[col * 2 + 0], w1 = Wd2[col * 2 + 1];
#pragma unroll
            for (int s = 0; s < 4; ++s)
#pragma unroll
                for (int r = 0; r < 4; ++r) {
                    float h = fmaxf(acc[s][t][r] + b1, 0.f);
                    part[s][r][0] += h * w0;
                    part[s][r][1] += h * w1;
                }
        }
#pragma unroll
        for (int m = 1; m < 16; m <<= 1)
#pragma unroll
            for (int s = 0; s < 4; ++s)
#pragma unroll
                for (int r = 0; r < 4; ++r) {
                    part[s][r][0] += __shfl_xor(part[s][r][0], m);
                    part[s][r][1] += __shfl_xor(part[s][r][1], m);
                }
        if (cc == 0) {
#pragma unroll
            for (int s = 0; s < 4; ++s)
#pragma unroll
                for (int r = 0; r < 4; ++r) {
                    int orow = s * 16 + gq * 4 + r;
                    lpart[w][orow][0] = part[s][r][0];
                    lpart[w][orow][1] = part[s][r][1];
                }
        }

        // --- tail: rowbases for tile k+2 into rb[par] (waits idx loads only;
        //     stage(k+1) stays in flight) ---
        if (tid < 192)
            rb[par][tid] = (sec == 2)
                               ? (unsigned long long)(dstc + (size_t)pic2v * HD)
                               : (unsigned long long)(feats + (((long)tload * NN + nload) * (long)HD));
        preg = preg2;

        // barrier 2: LDS-only drain (keep vmcnt pipeline alive)
        asm volatile("s_waitcnt lgkmcnt(0)" ::: "memory");
        __builtin_amdgcn_s_barrier();
        __builtin_amdgcn_sched_barrier(0);

        // --- per-tile output (wave 0) ---
        if (tid < 64) {
            int pi = tl * 64 + tid;
            if (pi < PP) {
                int p = pperm[pi];
                float l0 = lpart[0][tid][0] + lpart[1][tid][0] + lpart[2][tid][0] +
                           lpart[3][tid][0] + bd2[0];
                float l1 = lpart[0][tid][1] + lpart[1][tid][1] + lpart[2][tid][1] +
                           lpart[3][tid][1] + bd2[1];
                float m = fmaxf(l0, l1);
                float lse = m + logf(expf(l0 - m) + expf(l1 - m));
                float lp0 = l0 - lse, lp1 = l1 - lse;
                logprob[p * 2 + 0] = lp0;
                logprob[p * 2 + 1] = lp1;
                int g = group_id[p];
                atomicAdd(&group_sums[g * 2 + 0], lp0);
                atomicAdd(&group_sums[g * 2 + 1], lp1);
            }
        }
    }
#undef STAGE
}

// ------------------------------------------------------------------
// single block: counts total + segmented inclusive cumsum within variants
__global__ void within_total_k(const float* __restrict__ group_sums,
                               const int* __restrict__ var_rowptr,
                               const float* __restrict__ counts,
                               float* __restrict__ within, float* __restrict__ total) {
    __shared__ float buf[256];
    int tid = threadIdx.x;
    float s = 0.f;
    for (int i = tid; i < VV; i += 256) s += counts[i];
    buf[tid] = s;
    __syncthreads();
    for (int off = 128; off > 0; off >>= 1) {
        if (tid < off) buf[tid] += buf[tid + off];
        __syncthreads();
    }
    if (tid == 0) total[0] = buf[0];
    for (int v = tid; v < VV; v += 256) {
        int gs = var_rowptr[v], ge = var_rowptr[v + 1];
        float r0 = 0.f, r1 = 0.f;
        for (int g = gs; g < ge; ++g) {
            r0 += group_sums[2 * g + 0];
            r1 += group_sums[2 * g + 1];
            within[2 * g + 0] = r0;
            within[2 * g + 1] = r1;
        }
    }
}

__global__ void final_k(const float* __restrict__ logprob, const float* __restrict__ within,
                        const int* __restrict__ group_id, const int* __restrict__ vog,
                        const float* __restrict__ counts, const float* __restrict__ total,
                        const int* __restrict__ place_idx, float* __restrict__ outp) {
    int p = blockIdx.x * blockDim.x + threadIdx.x;
    if (p >= PP) return;
    int g = group_id[p];
    int v = vog[g];
    float lc = logf(counts[v]) - logf(total[0]);
    int node = place_idx[p];
    atomicAdd(&outp[node * 2 + 0], logprob[p * 2 + 0] + within[g * 2 + 0] + lc);
    atomicAdd(&outp[node * 2 + 1], logprob[p * 2 + 1] + within[g * 2 + 1] + lc);
}

// ------------------------------------------------------------------
extern "C" void kernel_launch(void* const* d_in, const int* in_sizes, int n_in,
                              void* d_out, int out_size, void* d_ws, size_t ws_size,
                              hipStream_t stream) {
    const float* x          = (const float*)d_in[0];
    const float* W_enc_self = (const float*)d_in[1];
    const float* W_enc_nei  = (const float*)d_in[2];
    const float* b_enc      = (const float*)d_in[3];
    const float* W2_self    = (const float*)d_in[4];
    const float* W2_nei     = (const float*)d_in[5];
    const float* b2         = (const float*)d_in[6];
    const float* Wd1        = (const float*)d_in[7];
    const float* bd1        = (const float*)d_in[8];
    const float* Wd2        = (const float*)d_in[9];
    const float* bd2        = (const float*)d_in[10];
    const float* counts     = (const float*)d_in[11];
    const int* edge_src     = (const int*)d_in[12];
    const int* edge_dst     = (const int*)d_in[13];
    const int* place_idx    = (const int*)d_in[14];
    const int* src_idx      = (const int*)d_in[15];
    const int* t_idx        = (const int*)d_in[16];
    const int* dst_nodes    = (const int*)d_in[17];
    const int* dst_seg      = (const int*)d_in[18];
    const int* group_id     = (const int*)d_in[19];
    const int* variant_of_group = (const int*)d_in[20];
    float* outp = (float*)d_out;

    const int NB = (NN + 255) / 256;   // 196 scan blocks

    // ---- workspace layout (R10-identical) ----
    unsigned short* feats = (unsigned short*)d_ws;              // 9*N*H bf16
    unsigned short* aggb  = feats + (size_t)(TT + 1) * NN * HD; // N*H
    unsigned short* xb    = aggb + (size_t)NN * HD;             // N*FIN
    unsigned short* dstc  = xb + (size_t)NN * FINN;             // P*H bf16 (pperm-compact)
    unsigned short* wenc_t = dstc + (size_t)PP * HD;            // 128*128
    unsigned short* w2_t   = wenc_t + HD * 2 * FINN;            // 128*256
    unsigned short* wd1t   = w2_t + HD * 2 * HD;                // 384*384
    int* zr = (int*)(wd1t + 384 * 384);                         // zero-region start
    int* csr_counts   = zr;                                     // N
    int* csr_cursor   = csr_counts + NN;                        // N
    float* group_sums = (float*)(csr_cursor + NN);              // 2G
    int* hist9        = (int*)(group_sums + 2 * GG);            // 9
    int* cursor9      = hist9 + 9;                              // 9
    size_t zero_words = (size_t)NN + NN + 2 * GG + 18;
    int* bsum       = cursor9 + 9;                              // 256
    int* boff       = bsum + 256;                               // 256
    int* boff9      = boff + 256;                               // 9 (+pad 7)
    int* csr_rowptr = boff9 + 16;                               // N+1
    int* dst_rowptr = csr_rowptr + (NN + 1);                    // P+1
    int* var_rowptr = dst_rowptr + (PP + 1);                    // V+1
    int* csr_src    = var_rowptr + (VV + 1);                    // E
    int* pperm      = csr_src + EE;                             // P
    float* logprob  = (float*)(pperm + PP);                     // 2P
    float* within   = logprob + 2 * PP;                         // 2G
    float* total_counts = within + 2 * GG;                      // 1

    hipMemsetAsync(zr, 0, zero_words * 4, stream);
    hipMemsetAsync(d_out, 0, (size_t)out_size * sizeof(float), stream);

    // ---- fused prep + CSR builds + t-bucket permutation ----
    prep_k<<<(NN * FINN + 255) / 256, 256, 0, stream>>>(x, W_enc_self, W_enc_nei, W2_self,
                                                        W2_nei, Wd1, xb, wenc_t, w2_t, wd1t);
    count_k<<<(EE + 255) / 256, 256, 0, stream>>>(edge_dst, csr_counts, EE);
    blk_sum_k<<<NB, 256, 0, stream>>>(csr_counts, NN, bsum);
    scan_small_k<<<1, 256, 0, stream>>>(bsum, NB, boff);
    rowptr_fill_k<<<NB, 256, 0, stream>>>(csr_counts, boff, NN, csr_rowptr, EE);
    fill_csr_k<<<(EE + 255) / 256, 256, 0, stream>>>(edge_src, edge_dst, csr_rowptr,
                                                     csr_cursor, csr_src, EE);
    lb_rowptr_k<<<(PP + 256) / 256, 256, 0, stream>>>(dst_seg, DD, dst_rowptr, PP);
    lb_rowptr_k<<<(VV + 256) / 256, 256, 0, stream>>>(variant_of_group, GG, var_rowptr, VV);
    hist9_k<<<(PP + 255) / 256, 256, 0, stream>>>(t_idx, hist9);
    scan9_k<<<1, 64, 0, stream>>>(hist9, boff9);
    bucket_perm_k<<<(PP + 255) / 256, 256, 0, stream>>>(t_idx, boff9, cursor9, pperm);

    // ---- 9 message-passing rounds (R8-proven agg2 + wider-grid mp) ----
    for (int r = 0; r <= TT; ++r) {
        const unsigned short* hin = (r == 0) ? xb : feats + (size_t)(r - 1) * NN * HD;
        unsigned short* hout = feats + (size_t)r * NN * HD;
        if (r == 0) {
            agg2_k<FINN><<<(NN + 3) / 4, 256, 0, stream>>>(hin, csr_rowptr, csr_src, aggb);
            mp_mfma_k<<<(NN + 31) / 32, 128, 0, stream>>>(hin, aggb, wenc_t, b_enc, hout, FINN);
        } else {
            agg2_k<HD><<<(NN + 3) / 4, 256, 0, stream>>>(hin, csr_rowptr, csr_src, aggb);
            mp_mfma_k<<<(NN + 31) / 32, 128, 0, stream>>>(hin, aggb, w2_t, b2, hout, HD);
        }
    }

    // ---- dst segment-sum (pperm-compact) + persistent pipelined dec4 ----
    dst_sum_k<<<(PP + 3) / 4, 256, 0, stream>>>(feats, t_idx, dst_nodes, dst_rowptr, pperm, dstc);
    dec4_k<<<DEC_GRID, 256, 0, stream>>>(feats, dstc, place_idx, src_idx, t_idx,
                                         group_id, pperm, wd1t, bd1, Wd2, bd2,
                                         logprob, group_sums);

    // ---- tail ----
    within_total_k<<<1, 256, 0, stream>>>(group_sums, var_rowptr, counts, within, total_counts);
    final_k<<<(PP + 255) / 256, 256, 0, stream>>>(logprob, within, group_id, variant_of_group,
                                                  counts, total_counts, place_idx, outp);
}

// Round 3
// 1048.670 us; speedup vs baseline: 1.1215x; 1.0340x over previous
//
#include <hip/hip_runtime.h>
#include <math.h>

#define NN 50000
#define FINN 64
#define HD 128
#define EE 800000
#define TT 8
#define PP 250000
#define DD 500000
#define GG 20000
#define VV 2000
#define OO 2

#define DEC_GRID 256
#define DEC_TILES ((PP + 63) / 64)

typedef short short8 __attribute__((ext_vector_type(8)));
typedef float f32x4 __attribute__((ext_vector_type(4)));

__device__ __forceinline__ unsigned short f2bf(float f) {
    unsigned int u = __float_as_uint(f);
    u += 0x7fffu + ((u >> 16) & 1u);   // round-to-nearest-even
    return (unsigned short)(u >> 16);
}
__device__ __forceinline__ float bf2f(unsigned short u) {
    return __uint_as_float(((unsigned int)u) << 16);
}

struct us8 { unsigned short v[8]; };

__device__ __forceinline__ void gload_lds16(const void* g, void* l) {
    __builtin_amdgcn_global_load_lds((__attribute__((address_space(1))) void*)g,
                                     (__attribute__((address_space(3))) void*)l, 16, 0, 0);
}

// ------------------------------------------------------------------
__global__ void count_k(const int* __restrict__ idx, int* __restrict__ counts, int n) {
    int i = blockIdx.x * blockDim.x + threadIdx.x;
    if (i < n) atomicAdd(&counts[idx[i]], 1);
}

// ---- 3-phase parallel exclusive scan for edge CSR rowptr ----
__global__ void blk_sum_k(const int* __restrict__ counts, int n, int* __restrict__ bsum) {
    __shared__ int buf[256];
    int t = threadIdx.x, i = blockIdx.x * 256 + t;
    buf[t] = (i < n) ? counts[i] : 0;
    __syncthreads();
    for (int off = 128; off > 0; off >>= 1) {
        if (t < off) buf[t] += buf[t + off];
        __syncthreads();
    }
    if (t == 0) bsum[blockIdx.x] = buf[0];
}

__global__ void scan_small_k(const int* __restrict__ bsum, int nb, int* __restrict__ boff) {
    __shared__ int buf[256];
    int t = threadIdx.x;
    int v = (t < nb) ? bsum[t] : 0;
    buf[t] = v;
    __syncthreads();
    for (int off = 1; off < 256; off <<= 1) {
        int u = (t >= off) ? buf[t - off] : 0;
        __syncthreads();
        buf[t] += u;
        __syncthreads();
    }
    if (t < nb) boff[t] = buf[t] - v;
}

__global__ void rowptr_fill_k(const int* __restrict__ counts, const int* __restrict__ boff,
                              int n, int* __restrict__ rowptr, int total) {
    __shared__ int buf[256];
    int t = threadIdx.x, i = blockIdx.x * 256 + t;
    int v = (i < n) ? counts[i] : 0;
    buf[t] = v;
    __syncthreads();
    for (int off = 1; off < 256; off <<= 1) {
        int u = (t >= off) ? buf[t - off] : 0;
        __syncthreads();
        buf[t] += u;
        __syncthreads();
    }
    if (i < n) rowptr[i] = boff[blockIdx.x] + buf[t] - v;
    if (i == 0) rowptr[n] = total;
}

// rowptr for SORTED arrays: rowptr[i] = lower_bound(arr, i), i in [0, m]
__global__ void lb_rowptr_k(const int* __restrict__ arr, int n, int* __restrict__ rowptr, int m) {
    int i = blockIdx.x * blockDim.x + threadIdx.x;
    if (i > m) return;
    int lo = 0, hi = n;
    while (lo < hi) {
        int mid = (lo + hi) >> 1;
        if (arr[mid] < i) lo = mid + 1; else hi = mid;
    }
    rowptr[i] = lo;
}

__global__ void fill_csr_k(const int* __restrict__ esrc, const int* __restrict__ edst,
                           const int* __restrict__ rowptr, int* __restrict__ cursor,
                           int* __restrict__ outi, int n) {
    int e = blockIdx.x * blockDim.x + threadIdx.x;
    if (e < n) {
        int d = edst[e];
        int pos = atomicAdd(&cursor[d], 1);
        outi[rowptr[d] + pos] = esrc[e];
    }
}

// ------------------------------------------------------------------
// t-bucket permutation
__global__ void hist9_k(const int* __restrict__ t_idx, int* __restrict__ hist) {
    __shared__ int l[9];
    if (threadIdx.x < 9) l[threadIdx.x] = 0;
    __syncthreads();
    int p = blockIdx.x * 256 + threadIdx.x;
    if (p < PP) atomicAdd(&l[t_idx[p]], 1);
    __syncthreads();
    if (threadIdx.x < 9) atomicAdd(&hist[threadIdx.x], l[threadIdx.x]);
}

__global__ void scan9_k(const int* __restrict__ hist, int* __restrict__ boff9) {
    if (threadIdx.x == 0) {
        int a = 0;
        for (int i = 0; i < 9; ++i) { boff9[i] = a; a += hist[i]; }
    }
}

__global__ void bucket_perm_k(const int* __restrict__ t_idx, const int* __restrict__ boff9,
                              int* __restrict__ cursor9, int* __restrict__ pperm) {
    __shared__ int lcnt[9];
    __shared__ int lbase[9];
    int tid = threadIdx.x;
    int p = blockIdx.x * 256 + tid;
    if (tid < 9) lcnt[tid] = 0;
    __syncthreads();
    int t = 0, lr = 0;
    bool ok = p < PP;
    if (ok) {
        t = t_idx[p];
        lr = atomicAdd(&lcnt[t], 1);
    }
    __syncthreads();
    if (tid < 9) lbase[tid] = atomicAdd(&cursor9[tid], lcnt[tid]);
    __syncthreads();
    if (ok) pperm[boff9[t] + lbase[t] + lr] = p;
}

// ------------------------------------------------------------------
// fused prep: x->bf16, both mp weight transposes, Wd1 transpose
__global__ void prep_k(const float* __restrict__ x,
                       const float* __restrict__ Wes, const float* __restrict__ Wen,
                       const float* __restrict__ W2s, const float* __restrict__ W2n,
                       const float* __restrict__ Wd1,
                       unsigned short* __restrict__ xb, unsigned short* __restrict__ wenc_t,
                       unsigned short* __restrict__ w2_t, unsigned short* __restrict__ wd1t) {
    int i = blockIdx.x * 256 + threadIdx.x;
    if (i < NN * FINN) xb[i] = f2bf(x[i]);
    if (i < HD * 2 * FINN) {
        int c = i / (2 * FINN), k = i - c * (2 * FINN);
        wenc_t[i] = f2bf((k < FINN) ? Wes[k * HD + c] : Wen[(k - FINN) * HD + c]);
    }
    if (i < HD * 2 * HD) {
        int c = i / (2 * HD), k = i - c * (2 * HD);
        w2_t[i] = f2bf((k < HD) ? W2s[k * HD + c] : W2n[(k - HD) * HD + c]);
    }
    if (i < 384 * 384) {
        int n = i / 384, k = i - n * 384;
        wd1t[i] = f2bf(Wd1[k * 384 + n]);
    }
}

// ------------------------------------------------------------------
// mean-aggregation, bf16 (R8-proven): 1 wave per node; 64/LPR sub-chains,
// depth-2 pipelined (2 row loads in flight per chain).
template <int KIN>
__launch_bounds__(256)
__global__ void agg2_k(const unsigned short* __restrict__ h, const int* __restrict__ rowptr,
                       const int* __restrict__ csr_src, unsigned short* __restrict__ aggout) {
    constexpr int LPR = KIN >> 3;      // lanes per row (ushort8 each)
    constexpr int EPW = 64 / LPR;      // chains per wave
    int node = blockIdx.x * 4 + (threadIdx.x >> 6);
    int lane = threadIdx.x & 63;
    int sub = lane / LPR;
    int fl = lane % LPR;
    if (node >= NN) return;
    int s = rowptr[node], e = rowptr[node + 1];
    float acc[8] = {};
    int i = s + sub;
    int iB = i + EPW;
    int srcA = (i < e) ? csr_src[i] : 0;
    int srcB = (iB < e) ? csr_src[iB] : 0;
    while (i < e) {
        bool hB = iB < e;
        us8 vA = *(const us8*)&h[(size_t)srcA * KIN + fl * 8];
        us8 vB;
        if (hB) vB = *(const us8*)&h[(size_t)srcB * KIN + fl * 8];
        int iN = iB + EPW, iN2 = iN + EPW;
        srcA = (iN < e) ? csr_src[iN] : 0;
        srcB = (iN2 < e) ? csr_src[iN2] : 0;
#pragma unroll
        for (int j = 0; j < 8; ++j) acc[j] += bf2f(vA.v[j]);
        if (hB) {
#pragma unroll
            for (int j = 0; j < 8; ++j) acc[j] += bf2f(vB.v[j]);
        }
        i = iN; iB = iN2;
    }
#pragma unroll
    for (int m = LPR; m < 64; m <<= 1)
#pragma unroll
        for (int j = 0; j < 8; ++j) acc[j] += __shfl_xor(acc[j], m);
    if (sub == 0) {
        float d = fmaxf((float)(e - s), 1.f);
        us8 o;
#pragma unroll
        for (int j = 0; j < 8; ++j) o.v[j] = f2bf(acc[j] / d);
        *(us8*)&aggout[(size_t)node * KIN + fl * 8] = o;
    }
}

// ------------------------------------------------------------------
// h_out = relu([hin | agg] @ Wt^T + b), bf16 MFMA, no LDS.
__launch_bounds__(128)
__global__ void mp_mfma_k(const unsigned short* __restrict__ hin,
                          const unsigned short* __restrict__ aggin,
                          const unsigned short* __restrict__ Wt,
                          const float* __restrict__ bias,
                          unsigned short* __restrict__ hout, int Kin) {
    int tid = threadIdx.x;
    int lane = tid & 63, w = tid >> 6;
    int cc = lane & 15, g = lane >> 4;
    int K = 2 * Kin;
    int rowA = blockIdx.x * 32 + w * 16 + cc;
    bool rowok = rowA < NN;
    const unsigned short* hrow = hin + (size_t)rowA * Kin;
    const unsigned short* arow = aggin + (size_t)rowA * Kin;

    f32x4 acc[8];
#pragma unroll
    for (int t = 0; t < 8; ++t) acc[t] = (f32x4){0.f, 0.f, 0.f, 0.f};

    for (int k0 = 0; k0 < K; k0 += 32) {
        int k = k0 + g * 8;
        short8 a = {0, 0, 0, 0, 0, 0, 0, 0};
        if (rowok)
            a = *(const short8*)((k < Kin) ? (hrow + k) : (arow + (k - Kin)));
#pragma unroll
        for (int t = 0; t < 8; ++t) {
            short8 b = *(const short8*)&Wt[(size_t)(t * 16 + cc) * K + k];
            acc[t] = __builtin_amdgcn_mfma_f32_16x16x32_bf16(a, b, acc[t], 0, 0, 0);
        }
    }
#pragma unroll
    for (int t = 0; t < 8; ++t) {
        int col = t * 16 + cc;
        float b1 = bias[col];
#pragma unroll
        for (int r = 0; r < 4; ++r) {
            int grow = blockIdx.x * 32 + w * 16 + g * 4 + r;
            if (grow < NN)
                hout[(size_t)grow * HD + col] = f2bf(fmaxf(acc[t][r] + b1, 0.f));
        }
    }
}

// ------------------------------------------------------------------
// dst segment-sum v2 -> dstc[pi][128] bf16 in pperm-compact order.
// avg segment degree = D/P = 2, so: one 16-lane group per prediction,
// in-lane accumulation (no shuffle reduce), depth-2 row pipeline.
// 16 predictions per 256-thread block -> all sub-groups busy.
__launch_bounds__(256)
__global__ void dst_sum2_k(const unsigned short* __restrict__ feats,
                           const int* __restrict__ t_idx, const int* __restrict__ dst_nodes,
                           const int* __restrict__ dst_rowptr, const int* __restrict__ pperm,
                           unsigned short* __restrict__ dstc) {
    int tid = threadIdx.x;
    int grp = tid >> 4;                 // 16 groups per block
    int fl = tid & 15;
    int pi = blockIdx.x * 16 + grp;
    if (pi >= PP) return;
    int p = pperm[pi];
    long t = t_idx[p];
    const unsigned short* base = feats + t * (long)NN * HD;
    int s = dst_rowptr[p], e = dst_rowptr[p + 1];
    float acc[8] = {};
    int i = s;
    int n0 = (i < e) ? dst_nodes[i] : 0;
    int n1 = (i + 1 < e) ? dst_nodes[i + 1] : 0;
    while (i < e) {
        bool h1 = (i + 1) < e;
        us8 v0 = *(const us8*)&base[(size_t)n0 * HD + fl * 8];
        us8 v1;
        if (h1) v1 = *(const us8*)&base[(size_t)n1 * HD + fl * 8];
        int i2 = i + 2, i3 = i + 3;
        n0 = (i2 < e) ? dst_nodes[i2] : 0;
        n1 = (i3 < e) ? dst_nodes[i3] : 0;
#pragma unroll
        for (int j = 0; j < 8; ++j) acc[j] += bf2f(v0.v[j]);
        if (h1) {
#pragma unroll
            for (int j = 0; j < 8; ++j) acc[j] += bf2f(v1.v[j]);
        }
        i = i2;
    }
    us8 o;
#pragma unroll
    for (int j = 0; j < 8; ++j) o.v[j] = f2bf(acc[j]);
    *(us8*)&dstc[(size_t)pi * HD + fl * 8] = o;
}

// ------------------------------------------------------------------
// dec5: persistent decoder, prefetch depth = 2 tiles (triple-buffered
// 3x48KB LDS A-panel). Counted waits vmcnt(27/18/6) are derived from the
// exact per-wave issue order: at wait(k) the ops newer than stage(k) are
// A(k-1)[3] + S(k+1)[12] + D(k-2)[~5, old] + A(k)[3] + S(k+2)[12]; the
// allowance is always <= that count, and every over-wait only touches ops
// >= 1 full tile old. Output phase (stores+atomics) runs AFTER barrier-1
// of the NEXT iteration against a double-buffered lpart, so its VMEM is a
// full compute-phase old before any wait can block on it; spread across
// all 4 waves (16 rows each). Compute phase has zero VMEM (breg-resident
// Wd1t), so it cannot disturb the vmcnt pipeline.
__launch_bounds__(256, 1)
__global__ void dec5_k(const unsigned short* __restrict__ feats,
                       const unsigned short* __restrict__ dstc,
                       const int* __restrict__ place_idx, const int* __restrict__ src_idx,
                       const int* __restrict__ t_idx, const int* __restrict__ group_id,
                       const int* __restrict__ pperm,
                       const unsigned short* __restrict__ Wd1t,
                       const float* __restrict__ bd1, const float* __restrict__ Wd2,
                       const float* __restrict__ bd2, float* __restrict__ logprob,
                       float* __restrict__ group_sums) {
    __shared__ unsigned short buf[3][192 * 128];          // 3 x 48 KB A-panel
    __shared__ unsigned long long rb[3][192];             // row-base ring
    __shared__ float lpart[2][4][64][2];                  // double-buffered partials

    int tid = threadIdx.x;
    int lane = tid & 63, w = tid >> 6;
    int cc = lane & 15, gq = lane >> 4;
    int cx7 = cc & 7;
    int bid = blockIdx.x;

    int row = min(tid, 191);
    int sec = row >> 6, pl = row & 63;
    const int* nptr = (sec == 0) ? place_idx : src_idx;

    int nt = (DEC_TILES - 1 - bid) / DEC_GRID + 1;        // tiles this block owns (>=15)

    float b20 = bd2[0], b21 = bd2[1];

    // ---- prologue: rowbases for tiles 0..2; pperm chase for tile 3 ----
    int pic0 = min((bid + 0 * DEC_GRID) * 64 + pl, PP - 1);
    int pic1 = min((bid + 1 * DEC_GRID) * 64 + pl, PP - 1);
    int pic2 = min((bid + 2 * DEC_GRID) * 64 + pl, PP - 1);
    int pA = pperm[pic0], pB = pperm[pic1], pC = pperm[pic2];
    int preg = pperm[min((bid + 3 * DEC_GRID) * 64 + pl, PP - 1)];
    if (tid < 192) {
        rb[0][tid] = (sec == 2) ? (unsigned long long)(dstc + (size_t)pic0 * HD)
                                : (unsigned long long)(feats + (((long)t_idx[pA] * NN + nptr[pA]) * (long)HD));
        rb[1][tid] = (sec == 2) ? (unsigned long long)(dstc + (size_t)pic1 * HD)
                                : (unsigned long long)(feats + (((long)t_idx[pB] * NN + nptr[pB]) * (long)HD));
        rb[2][tid] = (sec == 2) ? (unsigned long long)(dstc + (size_t)pic2 * HD)
                                : (unsigned long long)(feats + (((long)t_idx[pC] * NN + nptr[pC]) * (long)HD));
    }

    // ---- B-operand into registers (block-invariant) ----
    short8 breg[72];
    {
        const unsigned short* bbase = Wd1t + ((long)(w * 96 + cc) * 384 + gq * 8);
#pragma unroll
        for (int kk = 0; kk < 12; ++kk)
#pragma unroll
            for (int t = 0; t < 6; ++t)
                breg[kk * 6 + t] = *(const short8*)(bbase + (long)t * 16 * 384 + kk * 32);
    }
    __syncthreads();   // prologue full drain (once)

    int rsub = lane >> 4, chunk = lane & 15;

#define STAGE(slot_)                                                                 \
    {                                                                                \
        _Pragma("unroll")                                                            \
        for (int i = 0; i < 12; ++i) {                                               \
            int r = w * 48 + i * 4 + rsub;                                           \
            const unsigned short* src =                                              \
                (const unsigned short*)rb[slot_][r] + ((chunk ^ (r & 7)) * 8);       \
            gload_lds16(src, &buf[slot_][(w * 48 + i * 4) * 128]);                   \
        }                                                                            \
    }

#define OUTPUT(tlo_, po_)                                                            \
    if (lane < 16) {                                                                 \
        int orow = w * 16 + cc;                                                      \
        int pi = (tlo_) * 64 + orow;                                                 \
        if (pi < PP) {                                                               \
            int p = pperm[pi];                                                       \
            float l0 = lpart[po_][0][orow][0] + lpart[po_][1][orow][0] +             \
                       lpart[po_][2][orow][0] + lpart[po_][3][orow][0] + b20;        \
            float l1 = lpart[po_][0][orow][1] + lpart[po_][1][orow][1] +             \
                       lpart[po_][2][orow][1] + lpart[po_][3][orow][1] + b21;        \
            float mm = fmaxf(l0, l1);                                                \
            float lse = mm + logf(expf(l0 - mm) + expf(l1 - mm));                    \
            float lp0 = l0 - lse, lp1 = l1 - lse;                                    \
            logprob[p * 2 + 0] = lp0;                                                \
            logprob[p * 2 + 1] = lp1;                                                \
            int g = group_id[p];                                                     \
            atomicAdd(&group_sums[g * 2 + 0], lp0);                                  \
            atomicAdd(&group_sums[g * 2 + 1], lp1);                                  \
        }                                                                            \
    }

    STAGE(0);
    STAGE(1);

    for (int k = 0; k < nt; ++k) {
        int par = k % 3;

        // --- A: idx loads for tile k+3 (3 VMEM) ---
        int tload = t_idx[preg];
        int nload = nptr[preg];
        int preg2 = pperm[min((bid + (k + 4) * DEC_GRID) * 64 + pl, PP - 1)];
        int picw = min((bid + (k + 3) * DEC_GRID) * 64 + pl, PP - 1);

        // --- B: stage tile k+2 (12 VMEM) ---
        if (k + 2 < nt) STAGE((k + 2) % 3);

        // --- counted wait: guarantees stage(k) complete, keeps the
        //     newer pipeline (up to 2 tiles of stages) in flight ---
        __builtin_amdgcn_sched_barrier(0);
        if (k + 2 < nt) {
            asm volatile("s_waitcnt vmcnt(27)" ::: "memory");
        } else if (k + 1 < nt) {
            asm volatile("s_waitcnt vmcnt(18)" ::: "memory");
        } else {
            asm volatile("s_waitcnt vmcnt(6)" ::: "memory");
        }
        __builtin_amdgcn_s_barrier();
        __builtin_amdgcn_sched_barrier(0);

        // --- output of tile k-1 (VMEM issued here is a full tile old at
        //     the next wait); reads lpart[(k-1)&1], epilogue writes k&1 ---
        if (k > 0) {
            int tprev = bid + (k - 1) * DEC_GRID;
            OUTPUT(tprev, (k - 1) & 1);
        }

        // --- compute tile k from buf[par] (zero VMEM) ---
        const unsigned short* bufc = &buf[par][0];
        f32x4 acc[4][6];
#pragma unroll
        for (int s = 0; s < 4; ++s)
#pragma unroll
            for (int t = 0; t < 6; ++t) acc[s][t] = (f32x4){0.f, 0.f, 0.f, 0.f};

#pragma unroll
        for (int kk = 0; kk < 12; ++kk) {
            int seck = kk >> 2;
            int cbase = (kk & 3) * 4 + gq;
            int coff = (cbase ^ cx7) * 8;
            short8 a_c[4];
#pragma unroll
            for (int s = 0; s < 4; ++s) {
                int lrow = seck * 64 + s * 16 + cc;
                a_c[s] = *(const short8*)&bufc[lrow * 128 + coff];
            }
#pragma unroll
            for (int t = 0; t < 6; ++t)
#pragma unroll
                for (int s = 0; s < 4; ++s)
                    acc[s][t] = __builtin_amdgcn_mfma_f32_16x16x32_bf16(a_c[s], breg[kk * 6 + t],
                                                                        acc[s][t], 0, 0, 0);
        }

        // --- epilogue: bias + relu + Wd2 partials, cc-lane reduce ---
        float part[4][4][2] = {};
#pragma unroll
        for (int t = 0; t < 6; ++t) {
            int col = w * 96 + t * 16 + cc;
            float b1 = bd1[col];
            float w0 = Wd2[col * 2 + 0], w1 = Wd2[col * 2 + 1];
#pragma unroll
            for (int s = 0; s < 4; ++s)
#pragma unroll
                for (int r = 0; r < 4; ++r) {
                    float h = fmaxf(acc[s][t][r] + b1, 0.f);
                    part[s][r][0] += h * w0;
                    part[s][r][1] += h * w1;
                }
        }
#pragma unroll
        for (int m = 1; m < 16; m <<= 1)
#pragma unroll
            for (int s = 0; s < 4; ++s)
#pragma unroll
                for (int r = 0; r < 4; ++r) {
                    part[s][r][0] += __shfl_xor(part[s][r][0], m);
                    part[s][r][1] += __shfl_xor(part[s][r][1], m);
                }
        if (cc == 0) {
#pragma unroll
            for (int s = 0; s < 4; ++s)
#pragma unroll
                for (int r = 0; r < 4; ++r) {
                    int orow = s * 16 + gq * 4 + r;
                    lpart[k & 1][w][orow][0] = part[s][r][0];
                    lpart[k & 1][w][orow][1] = part[s][r][1];
                }
        }

        // --- tail: rowbases for tile k+3 into rb[par] (frees slot k%3) ---
        if (tid < 192)
            rb[par][tid] = (sec == 2)
                               ? (unsigned long long)(dstc + (size_t)picw * HD)
                               : (unsigned long long)(feats + (((long)tload * NN + nload) * (long)HD));
        preg = preg2;

        // barrier 2: LDS-only drain (vmcnt pipeline stays alive)
        asm volatile("s_waitcnt lgkmcnt(0)" ::: "memory");
        __builtin_amdgcn_s_barrier();
        __builtin_amdgcn_sched_barrier(0);
    }

    // final output (tile nt-1)
    {
        int tlast = bid + (nt - 1) * DEC_GRID;
        OUTPUT(tlast, (nt - 1) & 1);
    }
#undef STAGE
#undef OUTPUT
}

// ------------------------------------------------------------------
// single block: counts total + segmented inclusive cumsum within variants
__global__ void within_total_k(const float* __restrict__ group_sums,
                               const int* __restrict__ var_rowptr,
                               const float* __restrict__ counts,
                               float* __restrict__ within, float* __restrict__ total) {
    __shared__ float buf[256];
    int tid = threadIdx.x;
    float s = 0.f;
    for (int i = tid; i < VV; i += 256) s += counts[i];
    buf[tid] = s;
    __syncthreads();
    for (int off = 128; off > 0; off >>= 1) {
        if (tid < off) buf[tid] += buf[tid + off];
        __syncthreads();
    }
    if (tid == 0) total[0] = buf[0];
    for (int v = tid; v < VV; v += 256) {
        int gs = var_rowptr[v], ge = var_rowptr[v + 1];
        float r0 = 0.f, r1 = 0.f;
        for (int g = gs; g < ge; ++g) {
            r0 += group_sums[2 * g + 0];
            r1 += group_sums[2 * g + 1];
            within[2 * g + 0] = r0;
            within[2 * g + 1] = r1;
        }
    }
}

__global__ void final_k(const float* __restrict__ logprob, const float* __restrict__ within,
                        const int* __restrict__ group_id, const int* __restrict__ vog,
                        const float* __restrict__ counts, const float* __restrict__ total,
                        const int* __restrict__ place_idx, float* __restrict__ outp) {
    int p = blockIdx.x * blockDim.x + threadIdx.x;
    if (p >= PP) return;
    int g = group_id[p];
    int v = vog[g];
    float lc = logf(counts[v]) - logf(total[0]);
    int node = place_idx[p];
    atomicAdd(&outp[node * 2 + 0], logprob[p * 2 + 0] + within[g * 2 + 0] + lc);
    atomicAdd(&outp[node * 2 + 1], logprob[p * 2 + 1] + within[g * 2 + 1] + lc);
}

// ------------------------------------------------------------------
extern "C" void kernel_launch(void* const* d_in, const int* in_sizes, int n_in,
                              void* d_out, int out_size, void* d_ws, size_t ws_size,
                              hipStream_t stream) {
    const float* x          = (const float*)d_in[0];
    const float* W_enc_self = (const float*)d_in[1];
    const float* W_enc_nei  = (const float*)d_in[2];
    const float* b_enc      = (const float*)d_in[3];
    const float* W2_self    = (const float*)d_in[4];
    const float* W2_nei     = (const float*)d_in[5];
    const float* b2         = (const float*)d_in[6];
    const float* Wd1        = (const float*)d_in[7];
    const float* bd1        = (const float*)d_in[8];
    const float* Wd2        = (const float*)d_in[9];
    const float* bd2        = (const float*)d_in[10];
    const float* counts     = (const float*)d_in[11];
    const int* edge_src     = (const int*)d_in[12];
    const int* edge_dst     = (const int*)d_in[13];
    const int* place_idx    = (const int*)d_in[14];
    const int* src_idx      = (const int*)d_in[15];
    const int* t_idx        = (const int*)d_in[16];
    const int* dst_nodes    = (const int*)d_in[17];
    const int* dst_seg      = (const int*)d_in[18];
    const int* group_id     = (const int*)d_in[19];
    const int* variant_of_group = (const int*)d_in[20];
    float* outp = (float*)d_out;

    const int NB = (NN + 255) / 256;   // 196 scan blocks

    // ---- workspace layout (R10-identical) ----
    unsigned short* feats = (unsigned short*)d_ws;              // 9*N*H bf16
    unsigned short* aggb  = feats + (size_t)(TT + 1) * NN * HD; // N*H
    unsigned short* xb    = aggb + (size_t)NN * HD;             // N*FIN
    unsigned short* dstc  = xb + (size_t)NN * FINN;             // P*H bf16 (pperm-compact)
    unsigned short* wenc_t = dstc + (size_t)PP * HD;            // 128*128
    unsigned short* w2_t   = wenc_t + HD * 2 * FINN;            // 128*256
    unsigned short* wd1t   = w2_t + HD * 2 * HD;                // 384*384
    int* zr = (int*)(wd1t + 384 * 384);                         // zero-region start
    int* csr_counts   = zr;                                     // N
    int* csr_cursor   = csr_counts + NN;                        // N
    float* group_sums = (float*)(csr_cursor + NN);              // 2G
    int* hist9        = (int*)(group_sums + 2 * GG);            // 9
    int* cursor9      = hist9 + 9;                              // 9
    size_t zero_words = (size_t)NN + NN + 2 * GG + 18;
    int* bsum       = cursor9 + 9;                              // 256
    int* boff       = bsum + 256;                               // 256
    int* boff9      = boff + 256;                               // 9 (+pad 7)
    int* csr_rowptr = boff9 + 16;                               // N+1
    int* dst_rowptr = csr_rowptr + (NN + 1);                    // P+1
    int* var_rowptr = dst_rowptr + (PP + 1);                    // V+1
    int* csr_src    = var_rowptr + (VV + 1);                    // E
    int* pperm      = csr_src + EE;                             // P
    float* logprob  = (float*)(pperm + PP);                     // 2P
    float* within   = logprob + 2 * PP;                         // 2G
    float* total_counts = within + 2 * GG;                      // 1

    hipMemsetAsync(zr, 0, zero_words * 4, stream);
    hipMemsetAsync(d_out, 0, (size_t)out_size * sizeof(float), stream);

    // ---- fused prep + CSR builds + t-bucket permutation ----
    prep_k<<<(NN * FINN + 255) / 256, 256, 0, stream>>>(x, W_enc_self, W_enc_nei, W2_self,
                                                        W2_nei, Wd1, xb, wenc_t, w2_t, wd1t);
    count_k<<<(EE + 255) / 256, 256, 0, stream>>>(edge_dst, csr_counts, EE);
    blk_sum_k<<<NB, 256, 0, stream>>>(csr_counts, NN, bsum);
    scan_small_k<<<1, 256, 0, stream>>>(bsum, NB, boff);
    rowptr_fill_k<<<NB, 256, 0, stream>>>(csr_counts, boff, NN, csr_rowptr, EE);
    fill_csr_k<<<(EE + 255) / 256, 256, 0, stream>>>(edge_src, edge_dst, csr_rowptr,
                                                     csr_cursor, csr_src, EE);
    lb_rowptr_k<<<(PP + 256) / 256, 256, 0, stream>>>(dst_seg, DD, dst_rowptr, PP);
    lb_rowptr_k<<<(VV + 256) / 256, 256, 0, stream>>>(variant_of_group, GG, var_rowptr, VV);
    hist9_k<<<(PP + 255) / 256, 256, 0, stream>>>(t_idx, hist9);
    scan9_k<<<1, 64, 0, stream>>>(hist9, boff9);
    bucket_perm_k<<<(PP + 255) / 256, 256, 0, stream>>>(t_idx, boff9, cursor9, pperm);

    // ---- 9 message-passing rounds (R8-proven agg2 + wider-grid mp) ----
    for (int r = 0; r <= TT; ++r) {
        const unsigned short* hin = (r == 0) ? xb : feats + (size_t)(r - 1) * NN * HD;
        unsigned short* hout = feats + (size_t)r * NN * HD;
        if (r == 0) {
            agg2_k<FINN><<<(NN + 3) / 4, 256, 0, stream>>>(hin, csr_rowptr, csr_src, aggb);
            mp_mfma_k<<<(NN + 31) / 32, 128, 0, stream>>>(hin, aggb, wenc_t, b_enc, hout, FINN);
        } else {
            agg2_k<HD><<<(NN + 3) / 4, 256, 0, stream>>>(hin, csr_rowptr, csr_src, aggb);
            mp_mfma_k<<<(NN + 31) / 32, 128, 0, stream>>>(hin, aggb, w2_t, b2, hout, HD);
        }
    }

    // ---- dst segment-sum v2 + deep-pipelined persistent dec5 ----
    dst_sum2_k<<<(PP + 15) / 16, 256, 0, stream>>>(feats, t_idx, dst_nodes, dst_rowptr, pperm, dstc);
    dec5_k<<<DEC_GRID, 256, 0, stream>>>(feats, dstc, place_idx, src_idx, t_idx,
                                         group_id, pperm, wd1t, bd1, Wd2, bd2,
                                         logprob, group_sums);

    // ---- tail ----
    within_total_k<<<1, 256, 0, stream>>>(group_sums, var_rowptr, counts, within, total_counts);
    final_k<<<(PP + 255) / 256, 256, 0, stream>>>(logprob, within, group_id, variant_of_group,
                                                  counts, total_counts, place_idx, outp);
}

// Round 4
// 989.702 us; speedup vs baseline: 1.1883x; 1.0596x over previous
//
#include <hip/hip_runtime.h>
#include <math.h>

#define NN 50000
#define FINN 64
#define HD 128
#define EE 800000
#define TT 8
#define PP 250000
#define DD 500000
#define GG 20000
#define VV 2000
#define OO 2

#define DEC_GRID 256
#define DEC_TILES ((PP + 63) / 64)

typedef short short8 __attribute__((ext_vector_type(8)));
typedef float f32x4 __attribute__((ext_vector_type(4)));

__device__ __forceinline__ unsigned short f2bf(float f) {
    unsigned int u = __float_as_uint(f);
    u += 0x7fffu + ((u >> 16) & 1u);   // round-to-nearest-even
    return (unsigned short)(u >> 16);
}
__device__ __forceinline__ float bf2f(unsigned short u) {
    return __uint_as_float(((unsigned int)u) << 16);
}

struct us8 { unsigned short v[8]; };

__device__ __forceinline__ void gload_lds16(const void* g, void* l) {
    __builtin_amdgcn_global_load_lds((__attribute__((address_space(1))) void*)g,
                                     (__attribute__((address_space(3))) void*)l, 16, 0, 0);
}

// ------------------------------------------------------------------
__global__ void count_k(const int* __restrict__ idx, int* __restrict__ counts, int n) {
    int i = blockIdx.x * blockDim.x + threadIdx.x;
    if (i < n) atomicAdd(&counts[idx[i]], 1);
}

__global__ void blk_sum_k(const int* __restrict__ counts, int n, int* __restrict__ bsum) {
    __shared__ int buf[256];
    int t = threadIdx.x, i = blockIdx.x * 256 + t;
    buf[t] = (i < n) ? counts[i] : 0;
    __syncthreads();
    for (int off = 128; off > 0; off >>= 1) {
        if (t < off) buf[t] += buf[t + off];
        __syncthreads();
    }
    if (t == 0) bsum[blockIdx.x] = buf[0];
}

__global__ void scan_small_k(const int* __restrict__ bsum, int nb, int* __restrict__ boff) {
    __shared__ int buf[256];
    int t = threadIdx.x;
    int v = (t < nb) ? bsum[t] : 0;
    buf[t] = v;
    __syncthreads();
    for (int off = 1; off < 256; off <<= 1) {
        int u = (t >= off) ? buf[t - off] : 0;
        __syncthreads();
        buf[t] += u;
        __syncthreads();
    }
    if (t < nb) boff[t] = buf[t] - v;
}

__global__ void rowptr_fill_k(const int* __restrict__ counts, const int* __restrict__ boff,
                              int n, int* __restrict__ rowptr, int total) {
    __shared__ int buf[256];
    int t = threadIdx.x, i = blockIdx.x * 256 + t;
    int v = (i < n) ? counts[i] : 0;
    buf[t] = v;
    __syncthreads();
    for (int off = 1; off < 256; off <<= 1) {
        int u = (t >= off) ? buf[t - off] : 0;
        __syncthreads();
        buf[t] += u;
        __syncthreads();
    }
    if (i < n) rowptr[i] = boff[blockIdx.x] + buf[t] - v;
    if (i == 0) rowptr[n] = total;
}

__global__ void lb_rowptr_k(const int* __restrict__ arr, int n, int* __restrict__ rowptr, int m) {
    int i = blockIdx.x * blockDim.x + threadIdx.x;
    if (i > m) return;
    int lo = 0, hi = n;
    while (lo < hi) {
        int mid = (lo + hi) >> 1;
        if (arr[mid] < i) lo = mid + 1; else hi = mid;
    }
    rowptr[i] = lo;
}

__global__ void fill_csr_k(const int* __restrict__ esrc, const int* __restrict__ edst,
                           const int* __restrict__ rowptr, int* __restrict__ cursor,
                           int* __restrict__ outi, int n) {
    int e = blockIdx.x * blockDim.x + threadIdx.x;
    if (e < n) {
        int d = edst[e];
        int pos = atomicAdd(&cursor[d], 1);
        outi[rowptr[d] + pos] = esrc[e];
    }
}

// ------------------------------------------------------------------
__global__ void hist9_k(const int* __restrict__ t_idx, int* __restrict__ hist) {
    __shared__ int l[9];
    if (threadIdx.x < 9) l[threadIdx.x] = 0;
    __syncthreads();
    int p = blockIdx.x * 256 + threadIdx.x;
    if (p < PP) atomicAdd(&l[t_idx[p]], 1);
    __syncthreads();
    if (threadIdx.x < 9) atomicAdd(&hist[threadIdx.x], l[threadIdx.x]);
}

__global__ void scan9_k(const int* __restrict__ hist, int* __restrict__ boff9) {
    if (threadIdx.x == 0) {
        int a = 0;
        for (int i = 0; i < 9; ++i) { boff9[i] = a; a += hist[i]; }
    }
}

__global__ void bucket_perm_k(const int* __restrict__ t_idx, const int* __restrict__ boff9,
                              int* __restrict__ cursor9, int* __restrict__ pperm) {
    __shared__ int lcnt[9];
    __shared__ int lbase[9];
    int tid = threadIdx.x;
    int p = blockIdx.x * 256 + tid;
    if (tid < 9) lcnt[tid] = 0;
    __syncthreads();
    int t = 0, lr = 0;
    bool ok = p < PP;
    if (ok) {
        t = t_idx[p];
        lr = atomicAdd(&lcnt[t], 1);
    }
    __syncthreads();
    if (tid < 9) lbase[tid] = atomicAdd(&cursor9[tid], lcnt[tid]);
    __syncthreads();
    if (ok) pperm[boff9[t] + lbase[t] + lr] = p;
}

// ------------------------------------------------------------------
__global__ void prep_k(const float* __restrict__ x,
                       const float* __restrict__ Wes, const float* __restrict__ Wen,
                       const float* __restrict__ W2s, const float* __restrict__ W2n,
                       const float* __restrict__ Wd1,
                       unsigned short* __restrict__ xb, unsigned short* __restrict__ wenc_t,
                       unsigned short* __restrict__ w2_t, unsigned short* __restrict__ wd1t) {
    int i = blockIdx.x * 256 + threadIdx.x;
    if (i < NN * FINN) xb[i] = f2bf(x[i]);
    if (i < HD * 2 * FINN) {
        int c = i / (2 * FINN), k = i - c * (2 * FINN);
        wenc_t[i] = f2bf((k < FINN) ? Wes[k * HD + c] : Wen[(k - FINN) * HD + c]);
    }
    if (i < HD * 2 * HD) {
        int c = i / (2 * HD), k = i - c * (2 * HD);
        w2_t[i] = f2bf((k < HD) ? W2s[k * HD + c] : W2n[(k - HD) * HD + c]);
    }
    if (i < 384 * 384) {
        int n = i / 384, k = i - n * 384;
        wd1t[i] = f2bf(Wd1[k * 384 + n]);
    }
}

// ------------------------------------------------------------------
// mpf: fused mean-agg + MFMA message-passing round.
// Phase A: 8 lanes per node gather-sum neighbor rows (depth-2 pipeline),
// mean, write bf16 to LDS with chunk^(row&7) swizzle.
// Phase B: [hin | sm_agg] @ Wt^T via MFMA (hin from global, agg from LDS).
template <int KIN>
__launch_bounds__(256)
__global__ void mpf_k(const unsigned short* __restrict__ hin,
                      const int* __restrict__ rowptr, const int* __restrict__ csr_src,
                      const unsigned short* __restrict__ Wt, const float* __restrict__ bias,
                      unsigned short* __restrict__ hout) {
    constexpr int CPL = KIN / 64;          // us8 chunks per lane (2 for 128, 1 for 64)
    __shared__ unsigned short sm[32 * KIN];
    int tid = threadIdx.x;
    int r = tid >> 3;                      // node row in block, 0..31
    int sl = tid & 7;
    int node = blockIdx.x * 32 + r;
    int rx = r & 7;

    if (node < NN) {
        int s = rowptr[node], e = rowptr[node + 1];
        float acc[8 * CPL] = {};
        int i = s, iB = s + 1;
        int srcA = (i < e) ? csr_src[i] : 0;
        int srcB = (iB < e) ? csr_src[iB] : 0;
        while (i < e) {
            bool hB = iB < e;
            us8 vA0, vA1, vB0, vB1;
            vA0 = *(const us8*)&hin[(size_t)srcA * KIN + sl * (8 * CPL)];
            if constexpr (CPL == 2) vA1 = *(const us8*)&hin[(size_t)srcA * KIN + sl * 16 + 8];
            if (hB) {
                vB0 = *(const us8*)&hin[(size_t)srcB * KIN + sl * (8 * CPL)];
                if constexpr (CPL == 2) vB1 = *(const us8*)&hin[(size_t)srcB * KIN + sl * 16 + 8];
            }
            int iN = i + 2, iN2 = i + 3;
            srcA = (iN < e) ? csr_src[iN] : 0;
            srcB = (iN2 < e) ? csr_src[iN2] : 0;
#pragma unroll
            for (int j = 0; j < 8; ++j) acc[j] += bf2f(vA0.v[j]);
            if constexpr (CPL == 2)
#pragma unroll
                for (int j = 0; j < 8; ++j) acc[8 + j] += bf2f(vA1.v[j]);
            if (hB) {
#pragma unroll
                for (int j = 0; j < 8; ++j) acc[j] += bf2f(vB0.v[j]);
                if constexpr (CPL == 2)
#pragma unroll
                    for (int j = 0; j < 8; ++j) acc[8 + j] += bf2f(vB1.v[j]);
            }
            i = iN; iB = iN2;
        }
        float d = fmaxf((float)(e - s), 1.f);
        us8 o0, o1;
#pragma unroll
        for (int j = 0; j < 8; ++j) o0.v[j] = f2bf(acc[j] / d);
        int c0 = sl * CPL;
        *(us8*)&sm[r * KIN + ((c0 ^ rx) * 8)] = o0;
        if constexpr (CPL == 2) {
#pragma unroll
            for (int j = 0; j < 8; ++j) o1.v[j] = f2bf(acc[8 + j] / d);
            *(us8*)&sm[r * KIN + (((c0 + 1) ^ rx) * 8)] = o1;
        }
    }
    __syncthreads();

    // ---- phase B: MFMA ----
    int lane = tid & 63, w = tid >> 6;
    int cc = lane & 15, gq = lane >> 4;
    constexpr int K = 2 * KIN;
    int rloc = (w & 1) * 16 + cc;
    int rowA = blockIdx.x * 32 + rloc;
    bool rowok = rowA < NN;
    const unsigned short* hrow = hin + (size_t)rowA * KIN;
    int ch = (w >> 1) * 64;
    int rlx = rloc & 7;

    f32x4 acc2[4];
#pragma unroll
    for (int t = 0; t < 4; ++t) acc2[t] = (f32x4){0.f, 0.f, 0.f, 0.f};

#pragma unroll
    for (int k0 = 0; k0 < K; k0 += 32) {
        int k = k0 + gq * 8;
        short8 a = {0, 0, 0, 0, 0, 0, 0, 0};
        if (rowok) {
            if (k0 < KIN) a = *(const short8*)(hrow + k);
            else {
                int chunk = (k - KIN) >> 3;
                a = *(const short8*)&sm[rloc * KIN + ((chunk ^ rlx) * 8)];
            }
        }
#pragma unroll
        for (int t = 0; t < 4; ++t) {
            short8 b = *(const short8*)&Wt[(size_t)(ch + t * 16 + cc) * K + k];
            acc2[t] = __builtin_amdgcn_mfma_f32_16x16x32_bf16(a, b, acc2[t], 0, 0, 0);
        }
    }
#pragma unroll
    for (int t = 0; t < 4; ++t) {
        int col = ch + t * 16 + cc;
        float b1 = bias[col];
#pragma unroll
        for (int rj = 0; rj < 4; ++rj) {
            int grow = blockIdx.x * 32 + (w & 1) * 16 + gq * 4 + rj;
            if (grow < NN)
                hout[(size_t)grow * HD + col] = f2bf(fmaxf(acc2[t][rj] + b1, 0.f));
        }
    }
}

// ------------------------------------------------------------------
// dst segment-sum v2 -> dstc[pi][128] bf16 in pperm-compact order.
__launch_bounds__(256)
__global__ void dst_sum2_k(const unsigned short* __restrict__ feats,
                           const int* __restrict__ t_idx, const int* __restrict__ dst_nodes,
                           const int* __restrict__ dst_rowptr, const int* __restrict__ pperm,
                           unsigned short* __restrict__ dstc) {
    int tid = threadIdx.x;
    int grp = tid >> 4;
    int fl = tid & 15;
    int pi = blockIdx.x * 16 + grp;
    if (pi >= PP) return;
    int p = pperm[pi];
    long t = t_idx[p];
    const unsigned short* base = feats + t * (long)NN * HD;
    int s = dst_rowptr[p], e = dst_rowptr[p + 1];
    float acc[8] = {};
    int i = s;
    int n0 = (i < e) ? dst_nodes[i] : 0;
    int n1 = (i + 1 < e) ? dst_nodes[i + 1] : 0;
    while (i < e) {
        bool h1 = (i + 1) < e;
        us8 v0 = *(const us8*)&base[(size_t)n0 * HD + fl * 8];
        us8 v1;
        if (h1) v1 = *(const us8*)&base[(size_t)n1 * HD + fl * 8];
        int i2 = i + 2, i3 = i + 3;
        n0 = (i2 < e) ? dst_nodes[i2] : 0;
        n1 = (i3 < e) ? dst_nodes[i3] : 0;
#pragma unroll
        for (int j = 0; j < 8; ++j) acc[j] += bf2f(v0.v[j]);
        if (h1) {
#pragma unroll
            for (int j = 0; j < 8; ++j) acc[j] += bf2f(v1.v[j]);
        }
        i = i2;
    }
    us8 o;
#pragma unroll
    for (int j = 0; j < 8; ++j) o.v[j] = f2bf(acc[j]);
    *(us8*)&dstc[(size_t)pi * HD + fl * 8] = o;
}

// ------------------------------------------------------------------
// dec6: persistent decoder with a genuinely clean pipeline.
// 8 waves x 512 threads; breg = 36 short8/lane (144 VGPR, fits); bd1/Wd2
// hoisted to prologue regs; OUTPUT deferred 2 tiles, its pperm/group_id
// pointer-chased 1-2 iters ahead -> output phase is stores/atomics only.
// All loop loads are consumed >=1 iter after issue, so every
// compiler-inserted wait is a no-op; the only waits are our counted ones.
// Per-wave VMEM/iter: A=5 idx, STAGE=6, OUT=4 (w<4). Counted allowances:
// k<2:17, steady:21 (= S(k+1)6+OUT4+A5+S(k+2)6), k=nt-2:15, k=nt-1:5.
__launch_bounds__(512, 2)
__global__ void dec6_k(const unsigned short* __restrict__ feats,   // == workspace base
                       const unsigned short* __restrict__ dstc,
                       const int* __restrict__ place_idx, const int* __restrict__ src_idx,
                       const int* __restrict__ t_idx, const int* __restrict__ group_id,
                       const int* __restrict__ pperm,
                       const unsigned short* __restrict__ Wd1t,
                       const float* __restrict__ bd1, const float* __restrict__ Wd2,
                       const float* __restrict__ bd2, float* __restrict__ logprob,
                       float* __restrict__ group_sums) {
    __shared__ unsigned short buf[3][192 * 128];     // 3 x 48 KB A-panels
    __shared__ unsigned int rb[3][192];              // byte offsets from feats
    __shared__ float lpart[3][8][64][2];             // triple-buffered partials

    int tid = threadIdx.x;
    int lane = tid & 63, w = tid >> 6;               // 8 waves
    int cc = lane & 15, gq = lane >> 4;
    int bid = blockIdx.x;

    int row = min(tid, 191);
    int sec = row >> 6, pl = row & 63;
    const int* nptr = (sec == 0) ? place_idx : src_idx;
    unsigned int dstc_off = (unsigned int)((const char*)dstc - (const char*)feats);

    int nt = (DEC_TILES - 1 - bid) / DEC_GRID + 1;   // >= 15
    float b20 = bd2[0], b21 = bd2[1];

    // ---- prologue: rb for tiles 0..2, chase regs, hoisted epilogue consts ----
    if (tid < 192) {
#pragma unroll
        for (int s3 = 0; s3 < 3; ++s3) {
            int pic = min((bid + s3 * DEC_GRID) * 64 + pl, PP - 1);
            int p = pperm[pic];
            rb[s3][tid] = (sec == 2) ? (dstc_off + (unsigned int)pic * 256u)
                                     : (unsigned int)(((unsigned)t_idx[p] * NN + (unsigned)nptr[p]) * 256u);
        }
    }
    int p3 = pperm[min((bid + 3 * DEC_GRID) * 64 + pl, PP - 1)];
    int tOld = t_idx[p3], nOld = nptr[p3];
    int pCur = pperm[min((bid + 4 * DEC_GRID) * 64 + pl, PP - 1)];
    int opPP = 0, opP = 0, ogP = 0;

    // B-operand: 36 short8/lane (block-invariant), cols w*48..w*48+47
    short8 breg[36];
    float b1r[3], w0r[3], w1r[3];
    {
        const unsigned short* bbase = Wd1t + ((long)(w * 48 + cc) * 384 + gq * 8);
#pragma unroll
        for (int kk = 0; kk < 12; ++kk)
#pragma unroll
            for (int t = 0; t < 3; ++t)
                breg[kk * 3 + t] = *(const short8*)(bbase + (long)t * 16 * 384 + kk * 32);
#pragma unroll
        for (int t = 0; t < 3; ++t) {
            int col = w * 48 + t * 16 + cc;
            b1r[t] = bd1[col];
            w0r[t] = Wd2[col * 2 + 0];
            w1r[t] = Wd2[col * 2 + 1];
        }
    }
    __syncthreads();   // full drain once

    int rsub = lane >> 4, chunk = lane & 15;

#define STAGE(slot_)                                                                 \
    {                                                                                \
        _Pragma("unroll")                                                            \
        for (int i = 0; i < 6; ++i) {                                                \
            int r = w * 24 + i * 4 + rsub;                                           \
            const char* src = (const char*)feats + rb[slot_][r] +                    \
                              ((unsigned)(chunk ^ (r & 7)) << 4);                    \
            gload_lds16(src, &buf[slot_][(w * 24 + i * 4) * 128]);                   \
        }                                                                            \
    }

#define OUTPUT(tile_, slot_, opv_, ogv_)                                             \
    {                                                                                \
        int pi = (bid + (tile_) * DEC_GRID) * 64 + w * 16 + cc;                      \
        if (pi < PP) {                                                               \
            float l0 = b20, l1 = b21;                                                \
            _Pragma("unroll")                                                        \
            for (int w2 = 0; w2 < 8; ++w2) {                                         \
                l0 += lpart[slot_][w2][w * 16 + cc][0];                              \
                l1 += lpart[slot_][w2][w * 16 + cc][1];                              \
            }                                                                        \
            float mm = fmaxf(l0, l1);                                                \
            float lse = mm + logf(expf(l0 - mm) + expf(l1 - mm));                    \
            float lp0 = l0 - lse, lp1 = l1 - lse;                                    \
            logprob[(opv_)*2 + 0] = lp0;                                             \
            logprob[(opv_)*2 + 1] = lp1;                                             \
            atomicAdd(&group_sums[(ogv_)*2 + 0], lp0);                               \
            atomicAdd(&group_sums[(ogv_)*2 + 1], lp1);                               \
        }                                                                            \
    }

    STAGE(0);
    STAGE(1);

    for (int k = 0; k < nt; ++k) {
        int slot = k % 3;

        // ---- A-phase: 5 per-wave idx loads, all consumed >=1 iter later ----
        int opN = pperm[min((bid + k * DEC_GRID) * 64 + (w & 3) * 16 + cc, PP - 1)];
        int ogN = group_id[opP];
        int pNew = pperm[min((bid + (k + 5) * DEC_GRID) * 64 + pl, PP - 1)];
        int tNew = t_idx[pCur];
        int nNew = nptr[pCur];
        __builtin_amdgcn_sched_barrier(0);

        // ---- stage tile k+2 ----
        if (k + 2 < nt) STAGE((k + 2) % 3);
        __builtin_amdgcn_sched_barrier(0);

        // ---- counted wait: S(k) complete, newer pipeline stays in flight ----
        if (k + 2 < nt) {
            if (k >= 2) { asm volatile("s_waitcnt vmcnt(21)" ::: "memory"); }
            else        { asm volatile("s_waitcnt vmcnt(17)" ::: "memory"); }
        } else if (k + 1 < nt) {
            asm volatile("s_waitcnt vmcnt(15)" ::: "memory");
        } else {
            asm volatile("s_waitcnt vmcnt(5)" ::: "memory");
        }
        __builtin_amdgcn_s_barrier();
        __builtin_amdgcn_sched_barrier(0);

        // ---- OUTPUT(k-2): stores + atomics only, indices 2 iters old ----
        if (k >= 2 && w < 4 && lane < 16) OUTPUT(k - 2, (k - 2) % 3, opPP, ogP);

        // ---- compute tile k from buf[slot]: zero VMEM ----
        {
            const unsigned short* bufc = &buf[slot][0];
            f32x4 acc[4][3];
#pragma unroll
            for (int s = 0; s < 4; ++s)
#pragma unroll
                for (int t = 0; t < 3; ++t) acc[s][t] = (f32x4){0.f, 0.f, 0.f, 0.f};

#pragma unroll
            for (int kk = 0; kk < 12; ++kk) {
                int seck = kk >> 2;
                int cbase = (kk & 3) * 4 + gq;
                int coff = (cbase ^ (cc & 7)) * 8;
                short8 a_c[4];
#pragma unroll
                for (int s = 0; s < 4; ++s) {
                    int lrow = seck * 64 + s * 16 + cc;
                    a_c[s] = *(const short8*)&bufc[lrow * 128 + coff];
                }
#pragma unroll
                for (int t = 0; t < 3; ++t)
#pragma unroll
                    for (int s = 0; s < 4; ++s)
                        acc[s][t] = __builtin_amdgcn_mfma_f32_16x16x32_bf16(
                            a_c[s], breg[kk * 3 + t], acc[s][t], 0, 0, 0);
            }

            // ---- epilogue: hoisted consts only (no VMEM) ----
            float part[4][4][2] = {};
#pragma unroll
            for (int t = 0; t < 3; ++t) {
#pragma unroll
                for (int s = 0; s < 4; ++s)
#pragma unroll
                    for (int r = 0; r < 4; ++r) {
                        float h = fmaxf(acc[s][t][r] + b1r[t], 0.f);
                        part[s][r][0] += h * w0r[t];
                        part[s][r][1] += h * w1r[t];
                    }
            }
#pragma unroll
            for (int m = 1; m < 16; m <<= 1)
#pragma unroll
                for (int s = 0; s < 4; ++s)
#pragma unroll
                    for (int r = 0; r < 4; ++r) {
                        part[s][r][0] += __shfl_xor(part[s][r][0], m);
                        part[s][r][1] += __shfl_xor(part[s][r][1], m);
                    }
            if (cc == 0) {
#pragma unroll
                for (int s = 0; s < 4; ++s)
#pragma unroll
                    for (int r = 0; r < 4; ++r) {
                        int orow = s * 16 + gq * 4 + r;
                        lpart[slot][w][orow][0] = part[s][r][0];
                        lpart[slot][w][orow][1] = part[s][r][1];
                    }
            }
        }

        // ---- tail: rb for tile k+3 (uses t/n loaded LAST iter) ----
        if (tid < 192) {
            int picw = min((bid + (k + 3) * DEC_GRID) * 64 + pl, PP - 1);
            rb[(k + 3) % 3][tid] = (sec == 2)
                ? (dstc_off + (unsigned int)picw * 256u)
                : (unsigned int)(((unsigned)tOld * NN + (unsigned)nOld) * 256u);
        }
        // rotate chase registers
        tOld = tNew; nOld = nNew; pCur = pNew;
        opPP = opP; opP = opN; ogP = ogN;

        asm volatile("s_waitcnt lgkmcnt(0)" ::: "memory");
        __builtin_amdgcn_s_barrier();
        __builtin_amdgcn_sched_barrier(0);
    }

    // ---- post-loop outputs: tiles nt-2, nt-1 ----
    if (w < 4 && lane < 16) {
        OUTPUT(nt - 2, (nt - 2) % 3, opPP, ogP);
        int ogLast = group_id[opP];
        OUTPUT(nt - 1, (nt - 1) % 3, opP, ogLast);
    }
#undef STAGE
#undef OUTPUT
}

// ------------------------------------------------------------------
__global__ void within_total_k(const float* __restrict__ group_sums,
                               const int* __restrict__ var_rowptr,
                               const float* __restrict__ counts,
                               float* __restrict__ within, float* __restrict__ total) {
    __shared__ float buf[256];
    int tid = threadIdx.x;
    float s = 0.f;
    for (int i = tid; i < VV; i += 256) s += counts[i];
    buf[tid] = s;
    __syncthreads();
    for (int off = 128; off > 0; off >>= 1) {
        if (tid < off) buf[tid] += buf[tid + off];
        __syncthreads();
    }
    if (tid == 0) total[0] = buf[0];
    for (int v = tid; v < VV; v += 256) {
        int gs = var_rowptr[v], ge = var_rowptr[v + 1];
        float r0 = 0.f, r1 = 0.f;
        for (int g = gs; g < ge; ++g) {
            r0 += group_sums[2 * g + 0];
            r1 += group_sums[2 * g + 1];
            within[2 * g + 0] = r0;
            within[2 * g + 1] = r1;
        }
    }
}

__global__ void final_k(const float* __restrict__ logprob, const float* __restrict__ within,
                        const int* __restrict__ group_id, const int* __restrict__ vog,
                        const float* __restrict__ counts, const float* __restrict__ total,
                        const int* __restrict__ place_idx, float* __restrict__ outp) {
    int p = blockIdx.x * blockDim.x + threadIdx.x;
    if (p >= PP) return;
    int g = group_id[p];
    int v = vog[g];
    float lc = logf(counts[v]) - logf(total[0]);
    int node = place_idx[p];
    atomicAdd(&outp[node * 2 + 0], logprob[p * 2 + 0] + within[g * 2 + 0] + lc);
    atomicAdd(&outp[node * 2 + 1], logprob[p * 2 + 1] + within[g * 2 + 1] + lc);
}

// ------------------------------------------------------------------
extern "C" void kernel_launch(void* const* d_in, const int* in_sizes, int n_in,
                              void* d_out, int out_size, void* d_ws, size_t ws_size,
                              hipStream_t stream) {
    const float* x          = (const float*)d_in[0];
    const float* W_enc_self = (const float*)d_in[1];
    const float* W_enc_nei  = (const float*)d_in[2];
    const float* b_enc      = (const float*)d_in[3];
    const float* W2_self    = (const float*)d_in[4];
    const float* W2_nei     = (const float*)d_in[5];
    const float* b2         = (const float*)d_in[6];
    const float* Wd1        = (const float*)d_in[7];
    const float* bd1        = (const float*)d_in[8];
    const float* Wd2        = (const float*)d_in[9];
    const float* bd2        = (const float*)d_in[10];
    const float* counts     = (const float*)d_in[11];
    const int* edge_src     = (const int*)d_in[12];
    const int* edge_dst     = (const int*)d_in[13];
    const int* place_idx    = (const int*)d_in[14];
    const int* src_idx      = (const int*)d_in[15];
    const int* t_idx        = (const int*)d_in[16];
    const int* dst_nodes    = (const int*)d_in[17];
    const int* dst_seg      = (const int*)d_in[18];
    const int* group_id     = (const int*)d_in[19];
    const int* variant_of_group = (const int*)d_in[20];
    float* outp = (float*)d_out;

    const int NB = (NN + 255) / 256;

    // ---- workspace layout (unchanged) ----
    unsigned short* feats = (unsigned short*)d_ws;              // 9*N*H bf16
    unsigned short* aggb  = feats + (size_t)(TT + 1) * NN * HD; // N*H (unused now)
    unsigned short* xb    = aggb + (size_t)NN * HD;             // N*FIN
    unsigned short* dstc  = xb + (size_t)NN * FINN;             // P*H bf16
    unsigned short* wenc_t = dstc + (size_t)PP * HD;            // 128*128
    unsigned short* w2_t   = wenc_t + HD * 2 * FINN;            // 128*256
    unsigned short* wd1t   = w2_t + HD * 2 * HD;                // 384*384
    int* zr = (int*)(wd1t + 384 * 384);
    int* csr_counts   = zr;                                     // N
    int* csr_cursor   = csr_counts + NN;                        // N
    float* group_sums = (float*)(csr_cursor + NN);              // 2G
    int* hist9        = (int*)(group_sums + 2 * GG);            // 9
    int* cursor9      = hist9 + 9;                              // 9
    size_t zero_words = (size_t)NN + NN + 2 * GG + 18;
    int* bsum       = cursor9 + 9;                              // 256
    int* boff       = bsum + 256;                               // 256
    int* boff9      = boff + 256;                               // 9 (+pad 7)
    int* csr_rowptr = boff9 + 16;                               // N+1
    int* dst_rowptr = csr_rowptr + (NN + 1);                    // P+1
    int* var_rowptr = dst_rowptr + (PP + 1);                    // V+1
    int* csr_src    = var_rowptr + (VV + 1);                    // E
    int* pperm      = csr_src + EE;                             // P
    float* logprob  = (float*)(pperm + PP);                     // 2P
    float* within   = logprob + 2 * PP;                         // 2G
    float* total_counts = within + 2 * GG;                      // 1

    hipMemsetAsync(zr, 0, zero_words * 4, stream);
    hipMemsetAsync(d_out, 0, (size_t)out_size * sizeof(float), stream);

    // ---- prep + CSR builds + t-bucket permutation ----
    prep_k<<<(NN * FINN + 255) / 256, 256, 0, stream>>>(x, W_enc_self, W_enc_nei, W2_self,
                                                        W2_nei, Wd1, xb, wenc_t, w2_t, wd1t);
    count_k<<<(EE + 255) / 256, 256, 0, stream>>>(edge_dst, csr_counts, EE);
    blk_sum_k<<<NB, 256, 0, stream>>>(csr_counts, NN, bsum);
    scan_small_k<<<1, 256, 0, stream>>>(bsum, NB, boff);
    rowptr_fill_k<<<NB, 256, 0, stream>>>(csr_counts, boff, NN, csr_rowptr, EE);
    fill_csr_k<<<(EE + 255) / 256, 256, 0, stream>>>(edge_src, edge_dst, csr_rowptr,
                                                     csr_cursor, csr_src, EE);
    lb_rowptr_k<<<(PP + 256) / 256, 256, 0, stream>>>(dst_seg, DD, dst_rowptr, PP);
    lb_rowptr_k<<<(VV + 256) / 256, 256, 0, stream>>>(variant_of_group, GG, var_rowptr, VV);
    hist9_k<<<(PP + 255) / 256, 256, 0, stream>>>(t_idx, hist9);
    scan9_k<<<1, 64, 0, stream>>>(hist9, boff9);
    bucket_perm_k<<<(PP + 255) / 256, 256, 0, stream>>>(t_idx, boff9, cursor9, pperm);

    // ---- 9 fused message-passing rounds ----
    const int NB32 = (NN + 31) / 32;
    for (int r = 0; r <= TT; ++r) {
        const unsigned short* hin = (r == 0) ? xb : feats + (size_t)(r - 1) * NN * HD;
        unsigned short* hout = feats + (size_t)r * NN * HD;
        if (r == 0)
            mpf_k<FINN><<<NB32, 256, 0, stream>>>(hin, csr_rowptr, csr_src, wenc_t, b_enc, hout);
        else
            mpf_k<HD><<<NB32, 256, 0, stream>>>(hin, csr_rowptr, csr_src, w2_t, b2, hout);
    }

    // ---- dst segment-sum + clean-pipelined persistent dec6 ----
    dst_sum2_k<<<(PP + 15) / 16, 256, 0, stream>>>(feats, t_idx, dst_nodes, dst_rowptr, pperm, dstc);
    dec6_k<<<DEC_GRID, 512, 0, stream>>>(feats, dstc, place_idx, src_idx, t_idx,
                                         group_id, pperm, wd1t, bd1, Wd2, bd2,
                                         logprob, group_sums);

    // ---- tail ----
    within_total_k<<<1, 256, 0, stream>>>(group_sums, var_rowptr, counts, within, total_counts);
    final_k<<<(PP + 255) / 256, 256, 0, stream>>>(logprob, within, group_id, variant_of_group,
                                                  counts, total_counts, place_idx, outp);
}

// Round 5
// 979.792 us; speedup vs baseline: 1.2004x; 1.0101x over previous
//
#include <hip/hip_runtime.h>
#include <math.h>

#define NN 50000
#define FINN 64
#define HD 128
#define EE 800000
#define TT 8
#define PP 250000
#define DD 500000
#define GG 20000
#define VV 2000
#define OO 2

#define DEC_GRID 256
#define DEC_TILES ((PP + 63) / 64)

typedef short short8 __attribute__((ext_vector_type(8)));
typedef float f32x4 __attribute__((ext_vector_type(4)));

__device__ __forceinline__ unsigned short f2bf(float f) {
    unsigned int u = __float_as_uint(f);
    u += 0x7fffu + ((u >> 16) & 1u);   // round-to-nearest-even
    return (unsigned short)(u >> 16);
}
__device__ __forceinline__ float bf2f(unsigned short u) {
    return __uint_as_float(((unsigned int)u) << 16);
}

struct us8 { unsigned short v[8]; };

__device__ __forceinline__ void gload_lds16(const void* g, void* l) {
    __builtin_amdgcn_global_load_lds((__attribute__((address_space(1))) void*)g,
                                     (__attribute__((address_space(3))) void*)l, 16, 0, 0);
}

// ------------------------------------------------------------------
__global__ void count_k(const int* __restrict__ idx, int* __restrict__ counts, int n) {
    int i = blockIdx.x * blockDim.x + threadIdx.x;
    if (i < n) atomicAdd(&counts[idx[i]], 1);
}

__global__ void blk_sum_k(const int* __restrict__ counts, int n, int* __restrict__ bsum) {
    __shared__ int buf[256];
    int t = threadIdx.x, i = blockIdx.x * 256 + t;
    buf[t] = (i < n) ? counts[i] : 0;
    __syncthreads();
    for (int off = 128; off > 0; off >>= 1) {
        if (t < off) buf[t] += buf[t + off];
        __syncthreads();
    }
    if (t == 0) bsum[blockIdx.x] = buf[0];
}

__global__ void scan_small_k(const int* __restrict__ bsum, int nb, int* __restrict__ boff) {
    __shared__ int buf[256];
    int t = threadIdx.x;
    int v = (t < nb) ? bsum[t] : 0;
    buf[t] = v;
    __syncthreads();
    for (int off = 1; off < 256; off <<= 1) {
        int u = (t >= off) ? buf[t - off] : 0;
        __syncthreads();
        buf[t] += u;
        __syncthreads();
    }
    if (t < nb) boff[t] = buf[t] - v;
}

__global__ void rowptr_fill_k(const int* __restrict__ counts, const int* __restrict__ boff,
                              int n, int* __restrict__ rowptr, int total) {
    __shared__ int buf[256];
    int t = threadIdx.x, i = blockIdx.x * 256 + t;
    int v = (i < n) ? counts[i] : 0;
    buf[t] = v;
    __syncthreads();
    for (int off = 1; off < 256; off <<= 1) {
        int u = (t >= off) ? buf[t - off] : 0;
        __syncthreads();
        buf[t] += u;
        __syncthreads();
    }
    if (i < n) rowptr[i] = boff[blockIdx.x] + buf[t] - v;
    if (i == 0) rowptr[n] = total;
}

__global__ void lb_rowptr_k(const int* __restrict__ arr, int n, int* __restrict__ rowptr, int m) {
    int i = blockIdx.x * blockDim.x + threadIdx.x;
    if (i > m) return;
    int lo = 0, hi = n;
    while (lo < hi) {
        int mid = (lo + hi) >> 1;
        if (arr[mid] < i) lo = mid + 1; else hi = mid;
    }
    rowptr[i] = lo;
}

__global__ void fill_csr_k(const int* __restrict__ esrc, const int* __restrict__ edst,
                           const int* __restrict__ rowptr, int* __restrict__ cursor,
                           int* __restrict__ outi, int n) {
    int e = blockIdx.x * blockDim.x + threadIdx.x;
    if (e < n) {
        int d = edst[e];
        int pos = atomicAdd(&cursor[d], 1);
        outi[rowptr[d] + pos] = esrc[e];
    }
}

// ------------------------------------------------------------------
__global__ void hist9_k(const int* __restrict__ t_idx, int* __restrict__ hist) {
    __shared__ int l[9];
    if (threadIdx.x < 9) l[threadIdx.x] = 0;
    __syncthreads();
    int p = blockIdx.x * 256 + threadIdx.x;
    if (p < PP) atomicAdd(&l[t_idx[p]], 1);
    __syncthreads();
    if (threadIdx.x < 9) atomicAdd(&hist[threadIdx.x], l[threadIdx.x]);
}

__global__ void scan9_k(const int* __restrict__ hist, int* __restrict__ boff9) {
    if (threadIdx.x == 0) {
        int a = 0;
        for (int i = 0; i < 9; ++i) { boff9[i] = a; a += hist[i]; }
    }
}

__global__ void bucket_perm_k(const int* __restrict__ t_idx, const int* __restrict__ boff9,
                              int* __restrict__ cursor9, int* __restrict__ pperm) {
    __shared__ int lcnt[9];
    __shared__ int lbase[9];
    int tid = threadIdx.x;
    int p = blockIdx.x * 256 + tid;
    if (tid < 9) lcnt[tid] = 0;
    __syncthreads();
    int t = 0, lr = 0;
    bool ok = p < PP;
    if (ok) {
        t = t_idx[p];
        lr = atomicAdd(&lcnt[t], 1);
    }
    __syncthreads();
    if (tid < 9) lbase[tid] = atomicAdd(&cursor9[tid], lcnt[tid]);
    __syncthreads();
    if (ok) pperm[boff9[t] + lbase[t] + lr] = p;
}

// ------------------------------------------------------------------
__global__ void prep_k(const float* __restrict__ x,
                       const float* __restrict__ Wes, const float* __restrict__ Wen,
                       const float* __restrict__ W2s, const float* __restrict__ W2n,
                       const float* __restrict__ Wd1,
                       unsigned short* __restrict__ xb, unsigned short* __restrict__ wenc_t,
                       unsigned short* __restrict__ w2_t, unsigned short* __restrict__ wd1t) {
    int i = blockIdx.x * 256 + threadIdx.x;
    if (i < NN * FINN) xb[i] = f2bf(x[i]);
    if (i < HD * 2 * FINN) {
        int c = i / (2 * FINN), k = i - c * (2 * FINN);
        wenc_t[i] = f2bf((k < FINN) ? Wes[k * HD + c] : Wen[(k - FINN) * HD + c]);
    }
    if (i < HD * 2 * HD) {
        int c = i / (2 * HD), k = i - c * (2 * HD);
        w2_t[i] = f2bf((k < HD) ? W2s[k * HD + c] : W2n[(k - HD) * HD + c]);
    }
    if (i < 384 * 384) {
        int n = i / 384, k = i - n * 384;
        wd1t[i] = f2bf(Wd1[k * 384 + n]);
    }
}

// ------------------------------------------------------------------
// mpf: fused mean-agg + MFMA message-passing round.
// Phase A: 8 lanes per node gather-sum neighbor rows, DEPTH-4 pipeline
// (4 rows in flight per lane-group), mean, write bf16 to LDS with
// chunk^(row&7) swizzle.  Phase B: [hin | sm_agg] @ Wt^T via MFMA.
template <int KIN>
__launch_bounds__(256)
__global__ void mpf_k(const unsigned short* __restrict__ hin,
                      const int* __restrict__ rowptr, const int* __restrict__ csr_src,
                      const unsigned short* __restrict__ Wt, const float* __restrict__ bias,
                      unsigned short* __restrict__ hout) {
    constexpr int CPL = KIN / 64;          // us8 chunks per lane (2 for 128, 1 for 64)
    __shared__ unsigned short sm[32 * KIN];
    int tid = threadIdx.x;
    int r = tid >> 3;                      // node row in block, 0..31
    int sl = tid & 7;
    int node = blockIdx.x * 32 + r;
    int rx = r & 7;

    if (node < NN) {
        int s = rowptr[node], e = rowptr[node + 1];
        float acc[8 * CPL] = {};
        int src0 = (s < e) ? csr_src[s] : 0;
        int src1 = (s + 1 < e) ? csr_src[s + 1] : 0;
        int src2 = (s + 2 < e) ? csr_src[s + 2] : 0;
        int src3 = (s + 3 < e) ? csr_src[s + 3] : 0;
        for (int i = s; i < e; i += 4) {
            int rem = e - i;
            us8 v0a, v0b, v1a, v1b, v2a, v2b, v3a, v3b;
            v0a = *(const us8*)&hin[(size_t)src0 * KIN + sl * (8 * CPL)];
            if constexpr (CPL == 2) v0b = *(const us8*)&hin[(size_t)src0 * KIN + sl * 16 + 8];
            if (rem > 1) {
                v1a = *(const us8*)&hin[(size_t)src1 * KIN + sl * (8 * CPL)];
                if constexpr (CPL == 2) v1b = *(const us8*)&hin[(size_t)src1 * KIN + sl * 16 + 8];
            }
            if (rem > 2) {
                v2a = *(const us8*)&hin[(size_t)src2 * KIN + sl * (8 * CPL)];
                if constexpr (CPL == 2) v2b = *(const us8*)&hin[(size_t)src2 * KIN + sl * 16 + 8];
            }
            if (rem > 3) {
                v3a = *(const us8*)&hin[(size_t)src3 * KIN + sl * (8 * CPL)];
                if constexpr (CPL == 2) v3b = *(const us8*)&hin[(size_t)src3 * KIN + sl * 16 + 8];
            }
            src0 = (i + 4 < e) ? csr_src[i + 4] : 0;
            src1 = (i + 5 < e) ? csr_src[i + 5] : 0;
            src2 = (i + 6 < e) ? csr_src[i + 6] : 0;
            src3 = (i + 7 < e) ? csr_src[i + 7] : 0;
#pragma unroll
            for (int j = 0; j < 8; ++j) acc[j] += bf2f(v0a.v[j]);
            if constexpr (CPL == 2)
#pragma unroll
                for (int j = 0; j < 8; ++j) acc[8 + j] += bf2f(v0b.v[j]);
            if (rem > 1) {
#pragma unroll
                for (int j = 0; j < 8; ++j) acc[j] += bf2f(v1a.v[j]);
                if constexpr (CPL == 2)
#pragma unroll
                    for (int j = 0; j < 8; ++j) acc[8 + j] += bf2f(v1b.v[j]);
            }
            if (rem > 2) {
#pragma unroll
                for (int j = 0; j < 8; ++j) acc[j] += bf2f(v2a.v[j]);
                if constexpr (CPL == 2)
#pragma unroll
                    for (int j = 0; j < 8; ++j) acc[8 + j] += bf2f(v2b.v[j]);
            }
            if (rem > 3) {
#pragma unroll
                for (int j = 0; j < 8; ++j) acc[j] += bf2f(v3a.v[j]);
                if constexpr (CPL == 2)
#pragma unroll
                    for (int j = 0; j < 8; ++j) acc[8 + j] += bf2f(v3b.v[j]);
            }
        }
        float d = fmaxf((float)(e - s), 1.f);
        us8 o0, o1;
#pragma unroll
        for (int j = 0; j < 8; ++j) o0.v[j] = f2bf(acc[j] / d);
        int c0 = sl * CPL;
        *(us8*)&sm[r * KIN + ((c0 ^ rx) * 8)] = o0;
        if constexpr (CPL == 2) {
#pragma unroll
            for (int j = 0; j < 8; ++j) o1.v[j] = f2bf(acc[8 + j] / d);
            *(us8*)&sm[r * KIN + (((c0 + 1) ^ rx) * 8)] = o1;
        }
    }
    __syncthreads();

    // ---- phase B: MFMA ----
    int lane = tid & 63, w = tid >> 6;
    int cc = lane & 15, gq = lane >> 4;
    constexpr int K = 2 * KIN;
    int rloc = (w & 1) * 16 + cc;
    int rowA = blockIdx.x * 32 + rloc;
    bool rowok = rowA < NN;
    const unsigned short* hrow = hin + (size_t)rowA * KIN;
    int ch = (w >> 1) * 64;
    int rlx = rloc & 7;

    f32x4 acc2[4];
#pragma unroll
    for (int t = 0; t < 4; ++t) acc2[t] = (f32x4){0.f, 0.f, 0.f, 0.f};

#pragma unroll
    for (int k0 = 0; k0 < K; k0 += 32) {
        int k = k0 + gq * 8;
        short8 a = {0, 0, 0, 0, 0, 0, 0, 0};
        if (rowok) {
            if (k0 < KIN) a = *(const short8*)(hrow + k);
            else {
                int chunk = (k - KIN) >> 3;
                a = *(const short8*)&sm[rloc * KIN + ((chunk ^ rlx) * 8)];
            }
        }
#pragma unroll
        for (int t = 0; t < 4; ++t) {
            short8 b = *(const short8*)&Wt[(size_t)(ch + t * 16 + cc) * K + k];
            acc2[t] = __builtin_amdgcn_mfma_f32_16x16x32_bf16(a, b, acc2[t], 0, 0, 0);
        }
    }
#pragma unroll
    for (int t = 0; t < 4; ++t) {
        int col = ch + t * 16 + cc;
        float b1 = bias[col];
#pragma unroll
        for (int rj = 0; rj < 4; ++rj) {
            int grow = blockIdx.x * 32 + (w & 1) * 16 + gq * 4 + rj;
            if (grow < NN)
                hout[(size_t)grow * HD + col] = f2bf(fmaxf(acc2[t][rj] + b1, 0.f));
        }
    }
}

// ------------------------------------------------------------------
// dst segment-sum v2 -> dstc[pi][128] bf16 in pperm-compact order.
__launch_bounds__(256)
__global__ void dst_sum2_k(const unsigned short* __restrict__ feats,
                           const int* __restrict__ t_idx, const int* __restrict__ dst_nodes,
                           const int* __restrict__ dst_rowptr, const int* __restrict__ pperm,
                           unsigned short* __restrict__ dstc) {
    int tid = threadIdx.x;
    int grp = tid >> 4;
    int fl = tid & 15;
    int pi = blockIdx.x * 16 + grp;
    if (pi >= PP) return;
    int p = pperm[pi];
    long t = t_idx[p];
    const unsigned short* base = feats + t * (long)NN * HD;
    int s = dst_rowptr[p], e = dst_rowptr[p + 1];
    float acc[8] = {};
    int i = s;
    int n0 = (i < e) ? dst_nodes[i] : 0;
    int n1 = (i + 1 < e) ? dst_nodes[i + 1] : 0;
    while (i < e) {
        bool h1 = (i + 1) < e;
        us8 v0 = *(const us8*)&base[(size_t)n0 * HD + fl * 8];
        us8 v1;
        if (h1) v1 = *(const us8*)&base[(size_t)n1 * HD + fl * 8];
        int i2 = i + 2, i3 = i + 3;
        n0 = (i2 < e) ? dst_nodes[i2] : 0;
        n1 = (i3 < e) ? dst_nodes[i3] : 0;
#pragma unroll
        for (int j = 0; j < 8; ++j) acc[j] += bf2f(v0.v[j]);
        if (h1) {
#pragma unroll
            for (int j = 0; j < 8; ++j) acc[j] += bf2f(v1.v[j]);
        }
        i = i2;
    }
    us8 o;
#pragma unroll
    for (int j = 0; j < 8; ++j) o.v[j] = f2bf(acc[j]);
    *(us8*)&dstc[(size_t)pi * HD + fl * 8] = o;
}

// ------------------------------------------------------------------
// dec7: dec6 pipeline with the register budget stated unambiguously:
// amdgpu_waves_per_eu(2,2) => 256-VGPR budget (8-wave block, 1 block/CU).
// breg = 36 short8 = 144 VGPR must NOT spill (R4: __launch_bounds__(512,2)
// capped at 128 and spilled breg -> FETCH doubled). Epilogue is per-s to
// keep peak pressure ~230. All counted vmcnt allowances verified against
// in-order retirement for both OUTPUT-waves (w<4) and non-OUTPUT waves.
__global__ void
__attribute__((amdgpu_flat_work_group_size(512, 512), amdgpu_waves_per_eu(2, 2)))
dec7_k(const unsigned short* __restrict__ feats,   // == workspace base
       const unsigned short* __restrict__ dstc,
       const int* __restrict__ place_idx, const int* __restrict__ src_idx,
       const int* __restrict__ t_idx, const int* __restrict__ group_id,
       const int* __restrict__ pperm,
       const unsigned short* __restrict__ Wd1t,
       const float* __restrict__ bd1, const float* __restrict__ Wd2,
       const float* __restrict__ bd2, float* __restrict__ logprob,
       float* __restrict__ group_sums) {
    __shared__ unsigned short buf[3][192 * 128];     // 3 x 48 KB A-panels
    __shared__ unsigned int rb[3][192];              // byte offsets from feats
    __shared__ float lpart[3][8][64][2];             // triple-buffered partials

    int tid = threadIdx.x;
    int lane = tid & 63, w = tid >> 6;               // 8 waves
    int cc = lane & 15, gq = lane >> 4;
    int bid = blockIdx.x;

    int row = min(tid, 191);
    int sec = row >> 6, pl = row & 63;
    const int* nptr = (sec == 0) ? place_idx : src_idx;
    unsigned int dstc_off = (unsigned int)((const char*)dstc - (const char*)feats);

    int nt = (DEC_TILES - 1 - bid) / DEC_GRID + 1;   // >= 15
    float b20 = bd2[0], b21 = bd2[1];

    // ---- prologue: rb for tiles 0..2, chase regs, hoisted epilogue consts ----
    if (tid < 192) {
#pragma unroll
        for (int s3 = 0; s3 < 3; ++s3) {
            int pic = min((bid + s3 * DEC_GRID) * 64 + pl, PP - 1);
            int p = pperm[pic];
            rb[s3][tid] = (sec == 2) ? (dstc_off + (unsigned int)pic * 256u)
                                     : (unsigned int)(((unsigned)t_idx[p] * NN + (unsigned)nptr[p]) * 256u);
        }
    }
    int p3 = pperm[min((bid + 3 * DEC_GRID) * 64 + pl, PP - 1)];
    int tOld = t_idx[p3], nOld = nptr[p3];
    int pCur = pperm[min((bid + 4 * DEC_GRID) * 64 + pl, PP - 1)];
    int opPP = 0, opP = 0, ogP = 0;

    // B-operand: 36 short8/lane (block-invariant), cols w*48..w*48+47
    short8 breg[36];
    float b1r[3], w0r[3], w1r[3];
    {
        const unsigned short* bbase = Wd1t + ((long)(w * 48 + cc) * 384 + gq * 8);
#pragma unroll
        for (int kk = 0; kk < 12; ++kk)
#pragma unroll
            for (int t = 0; t < 3; ++t)
                breg[kk * 3 + t] = *(const short8*)(bbase + (long)t * 16 * 384 + kk * 32);
#pragma unroll
        for (int t = 0; t < 3; ++t) {
            int col = w * 48 + t * 16 + cc;
            b1r[t] = bd1[col];
            w0r[t] = Wd2[col * 2 + 0];
            w1r[t] = Wd2[col * 2 + 1];
        }
    }
    __syncthreads();   // full drain once

    int rsub = lane >> 4, chunk = lane & 15;

#define STAGE(slot_)                                                                 \
    {                                                                                \
        _Pragma("unroll")                                                            \
        for (int i = 0; i < 6; ++i) {                                                \
            int r = w * 24 + i * 4 + rsub;                                           \
            const char* src = (const char*)feats + rb[slot_][r] +                    \
                              ((unsigned)(chunk ^ (r & 7)) << 4);                    \
            gload_lds16(src, &buf[slot_][(w * 24 + i * 4) * 128]);                   \
        }                                                                            \
    }

#define OUTPUT(tile_, slot_, opv_, ogv_)                                             \
    {                                                                                \
        int pi = (bid + (tile_) * DEC_GRID) * 64 + w * 16 + cc;                      \
        if (pi < PP) {                                                               \
            float l0 = b20, l1 = b21;                                                \
            _Pragma("unroll")                                                        \
            for (int w2 = 0; w2 < 8; ++w2) {                                         \
                l0 += lpart[slot_][w2][w * 16 + cc][0];                              \
                l1 += lpart[slot_][w2][w * 16 + cc][1];                              \
            }                                                                        \
            float mm = fmaxf(l0, l1);                                                \
            float lse = mm + logf(expf(l0 - mm) + expf(l1 - mm));                    \
            float lp0 = l0 - lse, lp1 = l1 - lse;                                    \
            logprob[(opv_)*2 + 0] = lp0;                                             \
            logprob[(opv_)*2 + 1] = lp1;                                             \
            atomicAdd(&group_sums[(ogv_)*2 + 0], lp0);                               \
            atomicAdd(&group_sums[(ogv_)*2 + 1], lp1);                               \
        }                                                                            \
    }

    STAGE(0);
    STAGE(1);

    for (int k = 0; k < nt; ++k) {
        int slot = k % 3;

        // ---- A-phase: 5 per-wave idx loads, all consumed >=1 iter later ----
        int opN = pperm[min((bid + k * DEC_GRID) * 64 + (w & 3) * 16 + cc, PP - 1)];
        int ogN = group_id[opP];
        int pNew = pperm[min((bid + (k + 5) * DEC_GRID) * 64 + pl, PP - 1)];
        int tNew = t_idx[pCur];
        int nNew = nptr[pCur];
        __builtin_amdgcn_sched_barrier(0);

        // ---- stage tile k+2 ----
        if (k + 2 < nt) STAGE((k + 2) % 3);
        __builtin_amdgcn_sched_barrier(0);

        // ---- counted wait: S(k) complete, newer pipeline stays in flight ----
        if (k + 2 < nt) {
            if (k >= 2) { asm volatile("s_waitcnt vmcnt(21)" ::: "memory"); }
            else        { asm volatile("s_waitcnt vmcnt(17)" ::: "memory"); }
        } else if (k + 1 < nt) {
            asm volatile("s_waitcnt vmcnt(15)" ::: "memory");
        } else {
            asm volatile("s_waitcnt vmcnt(5)" ::: "memory");
        }
        __builtin_amdgcn_s_barrier();
        __builtin_amdgcn_sched_barrier(0);

        // ---- OUTPUT(k-2): stores + atomics only, indices 2 iters old ----
        if (k >= 2 && w < 4 && lane < 16) OUTPUT(k - 2, (k - 2) % 3, opPP, ogP);

        // ---- compute tile k from buf[slot]: zero VMEM ----
        {
            const unsigned short* bufc = &buf[slot][0];
            f32x4 acc[4][3];
#pragma unroll
            for (int s = 0; s < 4; ++s)
#pragma unroll
                for (int t = 0; t < 3; ++t) acc[s][t] = (f32x4){0.f, 0.f, 0.f, 0.f};

#pragma unroll
            for (int kk = 0; kk < 12; ++kk) {
                int seck = kk >> 2;
                int cbase = (kk & 3) * 4 + gq;
                int coff = (cbase ^ (cc & 7)) * 8;
                short8 a_c[4];
#pragma unroll
                for (int s = 0; s < 4; ++s) {
                    int lrow = seck * 64 + s * 16 + cc;
                    a_c[s] = *(const short8*)&bufc[lrow * 128 + coff];
                }
#pragma unroll
                for (int t = 0; t < 3; ++t)
#pragma unroll
                    for (int s = 0; s < 4; ++s)
                        acc[s][t] = __builtin_amdgcn_mfma_f32_16x16x32_bf16(
                            a_c[s], breg[kk * 3 + t], acc[s][t], 0, 0, 0);
            }

            // ---- epilogue per s (caps register pressure; acc[s] dies per s) ----
#pragma unroll
            for (int s = 0; s < 4; ++s) {
                float p0[4], p1[4];
#pragma unroll
                for (int r = 0; r < 4; ++r) { p0[r] = 0.f; p1[r] = 0.f; }
#pragma unroll
                for (int t = 0; t < 3; ++t) {
#pragma unroll
                    for (int r = 0; r < 4; ++r) {
                        float h = fmaxf(acc[s][t][r] + b1r[t], 0.f);
                        p0[r] += h * w0r[t];
                        p1[r] += h * w1r[t];
                    }
                }
#pragma unroll
                for (int m = 1; m < 16; m <<= 1)
#pragma unroll
                    for (int r = 0; r < 4; ++r) {
                        p0[r] += __shfl_xor(p0[r], m);
                        p1[r] += __shfl_xor(p1[r], m);
                    }
                if (cc == 0) {
#pragma unroll
                    for (int r = 0; r < 4; ++r) {
                        int orow = s * 16 + gq * 4 + r;
                        lpart[slot][w][orow][0] = p0[r];
                        lpart[slot][w][orow][1] = p1[r];
                    }
                }
            }
        }

        // ---- tail: rb for tile k+3 (uses t/n loaded LAST iter) ----
        if (tid < 192) {
            int picw = min((bid + (k + 3) * DEC_GRID) * 64 + pl, PP - 1);
            rb[(k + 3) % 3][tid] = (sec == 2)
                ? (dstc_off + (unsigned int)picw * 256u)
                : (unsigned int)(((unsigned)tOld * NN + (unsigned)nOld) * 256u);
        }
        // rotate chase registers
        tOld = tNew; nOld = nNew; pCur = pNew;
        opPP = opP; opP = opN; ogP = ogN;

        asm volatile("s_waitcnt lgkmcnt(0)" ::: "memory");
        __builtin_amdgcn_s_barrier();
        __builtin_amdgcn_sched_barrier(0);
    }

    // ---- post-loop outputs: tiles nt-2, nt-1 ----
    if (w < 4 && lane < 16) {
        OUTPUT(nt - 2, (nt - 2) % 3, opPP, ogP);
        int ogLast = group_id[opP];
        OUTPUT(nt - 1, (nt - 1) % 3, opP, ogLast);
    }
#undef STAGE
#undef OUTPUT
}

// ------------------------------------------------------------------
__global__ void within_total_k(const float* __restrict__ group_sums,
                               const int* __restrict__ var_rowptr,
                               const float* __restrict__ counts,
                               float* __restrict__ within, float* __restrict__ total) {
    __shared__ float buf[256];
    int tid = threadIdx.x;
    float s = 0.f;
    for (int i = tid; i < VV; i += 256) s += counts[i];
    buf[tid] = s;
    __syncthreads();
    for (int off = 128; off > 0; off >>= 1) {
        if (tid < off) buf[tid] += buf[tid + off];
        __syncthreads();
    }
    if (tid == 0) total[0] = buf[0];
    for (int v = tid; v < VV; v += 256) {
        int gs = var_rowptr[v], ge = var_rowptr[v + 1];
        float r0 = 0.f, r1 = 0.f;
        for (int g = gs; g < ge; ++g) {
            r0 += group_sums[2 * g + 0];
            r1 += group_sums[2 * g + 1];
            within[2 * g + 0] = r0;
            within[2 * g + 1] = r1;
        }
    }
}

__global__ void final_k(const float* __restrict__ logprob, const float* __restrict__ within,
                        const int* __restrict__ group_id, const int* __restrict__ vog,
                        const float* __restrict__ counts, const float* __restrict__ total,
                        const int* __restrict__ place_idx, float* __restrict__ outp) {
    int p = blockIdx.x * blockDim.x + threadIdx.x;
    if (p >= PP) return;
    int g = group_id[p];
    int v = vog[g];
    float lc = logf(counts[v]) - logf(total[0]);
    int node = place_idx[p];
    atomicAdd(&outp[node * 2 + 0], logprob[p * 2 + 0] + within[g * 2 + 0] + lc);
    atomicAdd(&outp[node * 2 + 1], logprob[p * 2 + 1] + within[g * 2 + 1] + lc);
}

// ------------------------------------------------------------------
extern "C" void kernel_launch(void* const* d_in, const int* in_sizes, int n_in,
                              void* d_out, int out_size, void* d_ws, size_t ws_size,
                              hipStream_t stream) {
    const float* x          = (const float*)d_in[0];
    const float* W_enc_self = (const float*)d_in[1];
    const float* W_enc_nei  = (const float*)d_in[2];
    const float* b_enc      = (const float*)d_in[3];
    const float* W2_self    = (const float*)d_in[4];
    const float* W2_nei     = (const float*)d_in[5];
    const float* b2         = (const float*)d_in[6];
    const float* Wd1        = (const float*)d_in[7];
    const float* bd1        = (const float*)d_in[8];
    const float* Wd2        = (const float*)d_in[9];
    const float* bd2        = (const float*)d_in[10];
    const float* counts     = (const float*)d_in[11];
    const int* edge_src     = (const int*)d_in[12];
    const int* edge_dst     = (const int*)d_in[13];
    const int* place_idx    = (const int*)d_in[14];
    const int* src_idx      = (const int*)d_in[15];
    const int* t_idx        = (const int*)d_in[16];
    const int* dst_nodes    = (const int*)d_in[17];
    const int* dst_seg      = (const int*)d_in[18];
    const int* group_id     = (const int*)d_in[19];
    const int* variant_of_group = (const int*)d_in[20];
    float* outp = (float*)d_out;

    const int NB = (NN + 255) / 256;

    // ---- workspace layout (unchanged) ----
    unsigned short* feats = (unsigned short*)d_ws;              // 9*N*H bf16
    unsigned short* aggb  = feats + (size_t)(TT + 1) * NN * HD; // N*H (unused now)
    unsigned short* xb    = aggb + (size_t)NN * HD;             // N*FIN
    unsigned short* dstc  = xb + (size_t)NN * FINN;             // P*H bf16
    unsigned short* wenc_t = dstc + (size_t)PP * HD;            // 128*128
    unsigned short* w2_t   = wenc_t + HD * 2 * FINN;            // 128*256
    unsigned short* wd1t   = w2_t + HD * 2 * HD;                // 384*384
    int* zr = (int*)(wd1t + 384 * 384);
    int* csr_counts   = zr;                                     // N
    int* csr_cursor   = csr_counts + NN;                        // N
    float* group_sums = (float*)(csr_cursor + NN);              // 2G
    int* hist9        = (int*)(group_sums + 2 * GG);            // 9
    int* cursor9      = hist9 + 9;                              // 9
    size_t zero_words = (size_t)NN + NN + 2 * GG + 18;
    int* bsum       = cursor9 + 9;                              // 256
    int* boff       = bsum + 256;                               // 256
    int* boff9      = boff + 256;                               // 9 (+pad 7)
    int* csr_rowptr = boff9 + 16;                               // N+1
    int* dst_rowptr = csr_rowptr + (NN + 1);                    // P+1
    int* var_rowptr = dst_rowptr + (PP + 1);                    // V+1
    int* csr_src    = var_rowptr + (VV + 1);                    // E
    int* pperm      = csr_src + EE;                             // P
    float* logprob  = (float*)(pperm + PP);                     // 2P
    float* within   = logprob + 2 * PP;                         // 2G
    float* total_counts = within + 2 * GG;                      // 1

    hipMemsetAsync(zr, 0, zero_words * 4, stream);
    hipMemsetAsync(d_out, 0, (size_t)out_size * sizeof(float), stream);

    // ---- prep + CSR builds + t-bucket permutation ----
    prep_k<<<(NN * FINN + 255) / 256, 256, 0, stream>>>(x, W_enc_self, W_enc_nei, W2_self,
                                                        W2_nei, Wd1, xb, wenc_t, w2_t, wd1t);
    count_k<<<(EE + 255) / 256, 256, 0, stream>>>(edge_dst, csr_counts, EE);
    blk_sum_k<<<NB, 256, 0, stream>>>(csr_counts, NN, bsum);
    scan_small_k<<<1, 256, 0, stream>>>(bsum, NB, boff);
    rowptr_fill_k<<<NB, 256, 0, stream>>>(csr_counts, boff, NN, csr_rowptr, EE);
    fill_csr_k<<<(EE + 255) / 256, 256, 0, stream>>>(edge_src, edge_dst, csr_rowptr,
                                                     csr_cursor, csr_src, EE);
    lb_rowptr_k<<<(PP + 256) / 256, 256, 0, stream>>>(dst_seg, DD, dst_rowptr, PP);
    lb_rowptr_k<<<(VV + 256) / 256, 256, 0, stream>>>(variant_of_group, GG, var_rowptr, VV);
    hist9_k<<<(PP + 255) / 256, 256, 0, stream>>>(t_idx, hist9);
    scan9_k<<<1, 64, 0, stream>>>(hist9, boff9);
    bucket_perm_k<<<(PP + 255) / 256, 256, 0, stream>>>(t_idx, boff9, cursor9, pperm);

    // ---- 9 fused message-passing rounds (depth-4 gather pipeline) ----
    const int NB32 = (NN + 31) / 32;
    for (int r = 0; r <= TT; ++r) {
        const unsigned short* hin = (r == 0) ? xb : feats + (size_t)(r - 1) * NN * HD;
        unsigned short* hout = feats + (size_t)r * NN * HD;
        if (r == 0)
            mpf_k<FINN><<<NB32, 256, 0, stream>>>(hin, csr_rowptr, csr_src, wenc_t, b_enc, hout);
        else
            mpf_k<HD><<<NB32, 256, 0, stream>>>(hin, csr_rowptr, csr_src, w2_t, b2, hout);
    }

    // ---- dst segment-sum + clean-pipelined persistent dec7 ----
    dst_sum2_k<<<(PP + 15) / 16, 256, 0, stream>>>(feats, t_idx, dst_nodes, dst_rowptr, pperm, dstc);
    dec7_k<<<DEC_GRID, 512, 0, stream>>>(feats, dstc, place_idx, src_idx, t_idx,
                                         group_id, pperm, wd1t, bd1, Wd2, bd2,
                                         logprob, group_sums);

    // ---- tail ----
    within_total_k<<<1, 256, 0, stream>>>(group_sums, var_rowptr, counts, within, total_counts);
    final_k<<<(PP + 255) / 256, 256, 0, stream>>>(logprob, within, group_id, variant_of_group,
                                                  counts, total_counts, place_idx, outp);
}